// Round 11
// baseline (745.347 us; speedup 1.0000x reference)
//
#include <hip/hip_runtime.h>
#include <math.h>

#define Bb 4
#define Hh 8
#define NP 4096
#define PTOT 8192
#define NTOT 12288
#define DIM 512
#define DH 64
#define SCALE 0.125f
#define NCH 24
#define CHUNK 512

typedef __attribute__((ext_vector_type(8))) _Float16 f16x8;
typedef __attribute__((ext_vector_type(4))) _Float16 f16x4;
typedef __attribute__((ext_vector_type(4))) float f32x4;

// ---------------- workspace layout (float offsets) ----------------
#define SZ_K    (4ull*8*12288*64)      // 25,165,824
#define SZ_L    (32ull*64*64)          // 131,072
#define OFF_K    0ull
#define OFF_V    (OFF_K + SZ_K)
#define OFF_QL   (OFF_V + SZ_K)
#define OFF_KL   (OFF_QL + SZ_L)
#define OFF_A2   (OFF_KL + SZ_L)
#define OFF_T3   (OFF_A2 + SZ_L)
#define OFF_T2   (OFF_T3 + SZ_L)
#define OFF_MAX  (OFF_T2 + SZ_L)
#define OFF_OPRE (OFF_MAX + 16ull)
// total = 59,375,648 floats (237.5 MB) — proven fit.
// BTq aliases [OFF_QL...), BTo aliases kb (dead after k_sim3part).

__device__ __forceinline__ unsigned short hbits(_Float16 x) {
    union { _Float16 f; unsigned short u; } c; c.f = x; return c.u;
}

// ---------------- transpose + fp16-split weights -> frag-major BT [N/16][K/8][16][8] ------
__global__ __launch_bounds__(256) void k_cvtw(const float* __restrict__ w,
    _Float16* __restrict__ bh, _Float16* __restrict__ bl, int K, int N)
{
    __shared__ float t[64][65];
    const int n0 = blockIdx.x * 64, k0 = blockIdx.y * 64;
    const int tid = threadIdx.x;
    #pragma unroll
    for (int i = 0; i < 4; ++i) {
        int r = (tid >> 4) + i * 16;
        int c = (tid & 15) * 4;
        float4 v = *(const float4*)(w + (size_t)(k0 + r) * N + n0 + c);
        t[r][c] = v.x; t[r][c+1] = v.y; t[r][c+2] = v.z; t[r][c+3] = v.w;
    }
    __syncthreads();
    const int n = n0 + (tid >> 2), kq = k0 + (tid & 3) * 16;
    f16x8 h8[2], l8[2];
    #pragma unroll
    for (int j = 0; j < 16; ++j) {
        float a = t[(kq - k0) + j][n - n0];
        _Float16 hh = (_Float16)a;
        _Float16 ll = (_Float16)(a - (float)hh);
        h8[j >> 3][j & 7] = hh;
        l8[j >> 3][j & 7] = ll;
    }
    size_t o = ((size_t)(n >> 4) * (K >> 3) + (kq >> 3)) * 128 + (size_t)(n & 15) * 8;
    *(f16x8*)(bh + o) = h8[0]; *(f16x8*)(bh + o + 128) = h8[1];
    *(f16x8*)(bl + o) = l8[0]; *(f16x8*)(bl + o + 8 * 16) = l8[1];
}

// ---------------- fp16-split MFMA GEMM: A via LDS dbuf, B frag-direct w/ reg dbuf --------
__device__ __forceinline__ int hoff(int r, int slot) {
    return r * 32 + (((slot ^ (r >> 1)) & 3) << 3);
}

#define BLOAD(t, BH, BL)                                                              \
    {                                                                                 \
        int k8_ = (t) * 4 + kslot;                                                    \
        _Pragma("unroll")                                                             \
        for (int n_ = 0; n_ < 4; ++n_) {                                              \
            size_t bo_ = ((size_t)(nb_base + n_) * (DIM >> 3) + k8_) * 128            \
                         + (size_t)ll * 8;                                            \
            BH[n_] = *(const f16x8*)(BTh + bo_);                                      \
            BL[n_] = *(const f16x8*)(BTl + bo_);                                      \
        }                                                                             \
    }

#define GSTEP(t, BH, BL)                                                              \
    {                                                                                 \
        f16x8 afh[4], afl[4];                                                         \
        _Pragma("unroll")                                                             \
        for (int m_ = 0; m_ < 4; ++m_) {                                              \
            int o_ = hoff(wr * 64 + m_ * 16 + ll, kslot);                             \
            afh[m_] = *(const f16x8*)&Ah[cur][o_];                                    \
            afl[m_] = *(const f16x8*)&Al[cur][o_];                                    \
        }                                                                             \
        if ((t) < 15) WRITET(cur ^ 1);                                                \
        if ((t) < 14) LOADT(((t) + 2) * 32);                                          \
        _Pragma("unroll")                                                             \
        for (int n_ = 0; n_ < 4; ++n_)                                                \
            _Pragma("unroll")                                                         \
            for (int m_ = 0; m_ < 4; ++m_) {                                          \
                acc[m_][n_] = __builtin_amdgcn_mfma_f32_16x16x32_f16(afh[m_], BH[n_], acc[m_][n_], 0, 0, 0); \
                acc[m_][n_] = __builtin_amdgcn_mfma_f32_16x16x32_f16(afh[m_], BL[n_], acc[m_][n_], 0, 0, 0); \
                acc[m_][n_] = __builtin_amdgcn_mfma_f32_16x16x32_f16(afl[m_], BH[n_], acc[m_][n_], 0, 0, 0); \
            }                                                                         \
        cur ^= 1;                                                                     \
    }

template<int MODE>
__global__ __launch_bounds__(256) void k_gemm_split(
    const float* __restrict__ Asrc0, const float* __restrict__ Asrc1,
    const _Float16* __restrict__ BTh, const _Float16* __restrict__ BTl,
    float* __restrict__ out0, float* __restrict__ out1, float* __restrict__ out2)
{
    __shared__ __align__(16) _Float16 Ah[2][128 * 32], Al[2][128 * 32];
    const int NB = (MODE == 0) ? 12 : 4;
    const int id = blockIdx.x;
    const int w8 = id % (NB * 8);
    const int n0 = (w8 >> 3) * 128;
    const int m0 = ((id / (NB * 8)) * 8 + (w8 & 7)) * 128;
    const int tid = threadIdx.x;
    const int wv = tid >> 6, lane = tid & 63;
    const int wr = wv >> 1, wc = wv & 1;
    const int kslot = lane >> 4, ll = lane & 15;
    const int nb_base = (n0 >> 4) + wc * 4;

    int ar[2], asl[2];
    const float* aptr[2];
    #pragma unroll
    for (int i = 0; i < 2; ++i) {
        int id2 = tid + 256 * i;
        ar[i] = id2 >> 2; asl[i] = id2 & 3;
        int grow = m0 + ar[i];
        if (MODE == 0) {
            int bi = grow / NTOT;
            int pos = grow - bi * NTOT;
            aptr[i] = (pos < NP) ? (Asrc0 + ((size_t)bi * NP + pos) * DIM)
                                 : (Asrc1 + ((size_t)bi * PTOT + (pos - NP)) * DIM);
        } else {
            aptr[i] = Asrc0 + (size_t)grow * DIM;
        }
    }

    float4 a0[2], a1[2];
    auto LOADT = [&](int k0) {
        #pragma unroll
        for (int i = 0; i < 2; ++i) {
            a0[i] = *(const float4*)(aptr[i] + k0 + asl[i] * 8);
            a1[i] = *(const float4*)(aptr[i] + k0 + asl[i] * 8 + 4);
        }
    };
    auto WRITET = [&](int buf) {
        #pragma unroll
        for (int i = 0; i < 2; ++i) {
            f16x8 h, l;
            float vals[8] = {a0[i].x, a0[i].y, a0[i].z, a0[i].w,
                             a1[i].x, a1[i].y, a1[i].z, a1[i].w};
            #pragma unroll
            for (int j = 0; j < 8; ++j) {
                _Float16 hh = (_Float16)vals[j];
                h[j] = hh;
                l[j] = (_Float16)(vals[j] - (float)hh);
            }
            int o = hoff(ar[i], asl[i]);
            *(f16x8*)&Ah[buf][o] = h;
            *(f16x8*)&Al[buf][o] = l;
        }
    };

    LOADT(0);
    WRITET(0);
    LOADT(32);
    int cur = 0;

    f16x8 bh0[4], bl0[4], bh1[4], bl1[4];
    BLOAD(0, bh0, bl0);

    f32x4 acc[4][4] = {};
    #pragma unroll 1
    for (int t = 0; t < 16; t += 2) {
        __syncthreads();                 // A[cur] visible; B(t) arrived (vmcnt drained)
        BLOAD(t + 1, bh1, bl1);          // prefetch next B — full MFMA block to land
        GSTEP(t, bh0, bl0);
        __syncthreads();
        if (t + 2 < 16) BLOAD(t + 2, bh0, bl0);
        GSTEP(t + 1, bh1, bl1);
    }
    #pragma unroll
    for (int m = 0; m < 4; ++m) {
        #pragma unroll
        for (int n = 0; n < 4; ++n) {
            int gcol = n0 + wc * 64 + n * 16 + ll;
            int rbase = m0 + wr * 64 + m * 16 + (lane >> 4) * 4;
            if (MODE == 1) {
                #pragma unroll
                for (int r = 0; r < 4; ++r)
                    out0[(size_t)(rbase + r) * DIM + gcol] = acc[m][n][r];
            } else {
                int which = gcol >> 9, h = (gcol >> 6) & 7, d = gcol & 63;
                #pragma unroll
                for (int r = 0; r < 4; ++r) {
                    int row = rbase + r;
                    int bi = row / NTOT;
                    int p = row - bi * NTOT;
                    float v = acc[m][n][r];
                    if (which == 0) {
                        if (p < NP) out0[(((size_t)bi * Hh + h) * NP + p) * DH + d] = v * SCALE;
                    } else if (which == 1) {
                        out1[(((size_t)bi * Hh + h) * NTOT + p) * DH + d] = v;
                    } else {
                        out2[(((size_t)bi * Hh + h) * NTOT + p) * DH + d] = v;
                    }
                }
            }
        }
    }
}

// ---------------- K2: landmark means (vectorized) ----------------
__global__ __launch_bounds__(256) void k_land(const float* __restrict__ mq,
    const float* __restrict__ kb, float* __restrict__ ql, float* __restrict__ kl)
{
    __shared__ float part[16][64];
    int idx = blockIdx.x;
    const int tid = threadIdx.x;
    const int rg = tid >> 4, c4 = (tid & 15) << 2;
    const float* src;
    float* dst;
    int R; float sc;
    if (idx < 2048) {
        int bh = idx >> 6, i = idx & 63;
        src = mq + ((size_t)bh * NP + i * 64) * DH;
        dst = ql + ((size_t)bh * 64 + i) * 64;
        R = 64; sc = 1.f / 64.f;
    } else {
        idx -= 2048;
        int bh = idx >> 6, i = idx & 63;
        src = kb + ((size_t)bh * NTOT + i * 192) * DH;
        dst = kl + ((size_t)bh * 64 + i) * 64;
        R = 192; sc = 1.f / 192.f;
    }
    float4 a = make_float4(0.f, 0.f, 0.f, 0.f);
    for (int r = rg; r < R; r += 16) {
        float4 v = *(const float4*)(src + (size_t)r * DH + c4);
        a.x += v.x; a.y += v.y; a.z += v.z; a.w += v.w;
    }
    *(float4*)&part[rg][c4] = a;
    __syncthreads();
    if (tid < 64) {
        float s = 0.f;
        #pragma unroll
        for (int g = 0; g < 16; ++g) s += part[g][tid];
        dst[tid] = s * sc;
    }
}

// ---------------- K3: attn2 = softmax(q_l @ k_l^T); also zero-inits mx ----------------
__global__ __launch_bounds__(256) void k_sim2(const float* __restrict__ ql,
    const float* __restrict__ kl, float* __restrict__ a2, float* __restrict__ mx)
{
    __shared__ float qs[64][64];
    __shared__ float ks[64][65];
    __shared__ float S[64][65];
    const int tid = threadIdx.x;
    const int bh = blockIdx.x;
    if (bh == 0 && tid < 2) mx[tid] = 0.f;
    for (int e = tid; e < 4096; e += 256) {
        qs[e >> 6][e & 63] = ql[(size_t)bh * 4096 + e];
        ks[e >> 6][e & 63] = kl[(size_t)bh * 4096 + e];
    }
    __syncthreads();
    for (int sI = 0; sI < 16; ++sI) {
        int e = (sI << 8) + tid;
        int i = e >> 6, j = e & 63;
        float acc = 0.f;
        #pragma unroll 16
        for (int d = 0; d < 64; ++d) acc = fmaf(qs[i][d], ks[j][d], acc);
        S[i][j] = acc;
    }
    __syncthreads();
    const int wv = tid >> 6, lane = tid & 63;
    for (int i = wv; i < 64; i += 4) {
        float v = S[i][lane];
        float mxv = v;
        #pragma unroll
        for (int off = 32; off; off >>= 1) mxv = fmaxf(mxv, __shfl_xor(mxv, off));
        float p = expf(v - mxv);
        float sm = p;
        #pragma unroll
        for (int off = 32; off; off >>= 1) sm += __shfl_xor(sm, off);
        a2[((size_t)bh * 64 + i) * 64 + lane] = p / sm;
    }
}

// ---------------- K4: global max of row/col abs-sums of attn2 ----------------
__global__ __launch_bounds__(64) void k_maxes(const float* __restrict__ a2,
    float* __restrict__ mx)
{
    const int bh = blockIdx.x;
    const int i = threadIdx.x;
    const float* base = a2 + (size_t)bh * 4096;
    float cs = 0.f, rs = 0.f;
    for (int j = 0; j < 64; ++j) {
        cs += fabsf(base[i * 64 + j]);
        rs += fabsf(base[j * 64 + i]);
    }
    #pragma unroll
    for (int off = 32; off; off >>= 1) {
        cs = fmaxf(cs, __shfl_xor(cs, off));
        rs = fmaxf(rs, __shfl_xor(rs, off));
    }
    if (i == 0) {
        atomicMax((unsigned int*)&mx[0], __float_as_uint(cs));
        atomicMax((unsigned int*)&mx[1], __float_as_uint(rs));
    }
}

// ---------------- K5a: sim3 partials — fp16-split MFMA flash over a 512-row chunk ----------
__global__ __launch_bounds__(256) void k_sim3part(const float* __restrict__ qlg,
    const float* __restrict__ kb, const float* __restrict__ vb,
    float* __restrict__ pacc, float* __restrict__ pm, float* __restrict__ pl)
{
    __shared__ __align__(16) _Float16 qsh[4096], qsl[4096];
    __shared__ __align__(16) _Float16 kvh[4096], kvl[4096];
    __shared__ __align__(16) unsigned int pss[64][68];
    __shared__ float corr_s[64];
    const int bh = blockIdx.x, ch = blockIdx.y;
    const int tid = threadIdx.x;
    const int wv = tid >> 6, lane = tid & 63;
    const int lg = lane >> 4, ll = lane & 15;

    #pragma unroll
    for (int it = 0; it < 4; ++it) {
        int e = tid + 256 * it;
        int r = e >> 4, c0 = (e & 15) << 2;
        float4 qv = *(const float4*)(qlg + (size_t)bh * 4096 + r * 64 + c0);
        f16x4 h, l;
        float vals[4] = {qv.x, qv.y, qv.z, qv.w};
        #pragma unroll
        for (int i = 0; i < 4; ++i) {
            _Float16 hh = (_Float16)vals[i];
            h[i] = hh; l[i] = (_Float16)(vals[i] - (float)hh);
        }
        int off = r * 64 + (((c0 >> 3) ^ (r & 7)) << 3) + (c0 & 7);
        *(f16x4*)&qsh[off] = h;
        *(f16x4*)&qsl[off] = l;
    }

    const float* kc = kb + ((size_t)bh * NTOT + ch * CHUNK) * DH;
    const float* vc = vb + ((size_t)bh * NTOT + ch * CHUNK) * DH;

    float m_run = -INFINITY, l_run = 0.f;
    f32x4 acc_o[4] = {};

    for (int t = 0; t < CHUNK / 64; ++t) {
        __syncthreads();
        #pragma unroll
        for (int it = 0; it < 4; ++it) {
            int e = tid + 256 * it;
            int r = e >> 4, c0 = (e & 15) << 2;
            float4 kx = *(const float4*)(kc + (size_t)(t * 64 + r) * DH + c0);
            f16x4 h, l;
            float vals[4] = {kx.x, kx.y, kx.z, kx.w};
            #pragma unroll
            for (int i = 0; i < 4; ++i) {
                _Float16 hh = (_Float16)vals[i];
                h[i] = hh; l[i] = (_Float16)(vals[i] - (float)hh);
            }
            int off = r * 64 + (((c0 >> 3) ^ (r & 7)) << 3) + (c0 & 7);
            *(f16x4*)&kvh[off] = h;
            *(f16x4*)&kvl[off] = l;
        }
        __syncthreads();
        f32x4 accs[4] = {};
        #pragma unroll
        for (int ks = 0; ks < 2; ++ks) {
            int k0 = 32 * ks + (lg << 3);
            int brow = 16 * wv + ll;
            int boff = brow * 64 + (((k0 >> 3) ^ (brow & 7)) << 3);
            f16x8 bh8 = *(const f16x8*)&kvh[boff];
            f16x8 bl8 = *(const f16x8*)&kvl[boff];
            #pragma unroll
            for (int m = 0; m < 4; ++m) {
                int arow = 16 * m + ll;
                int aoff = arow * 64 + (((k0 >> 3) ^ (arow & 7)) << 3);
                f16x8 ah8 = *(const f16x8*)&qsh[aoff];
                f16x8 al8 = *(const f16x8*)&qsl[aoff];
                accs[m] = __builtin_amdgcn_mfma_f32_16x16x32_f16(ah8, bh8, accs[m], 0, 0, 0);
                accs[m] = __builtin_amdgcn_mfma_f32_16x16x32_f16(ah8, bl8, accs[m], 0, 0, 0);
                accs[m] = __builtin_amdgcn_mfma_f32_16x16x32_f16(al8, bh8, accs[m], 0, 0, 0);
            }
        }
        #pragma unroll
        for (int m = 0; m < 4; ++m)
            #pragma unroll
            for (int rg = 0; rg < 4; ++rg)
                pss[16 * m + lg * 4 + rg][16 * wv + ll] = __float_as_uint(accs[m][rg]);
        __syncthreads();
        {
            const int r = tid >> 2, q = tid & 3;
            float s[16];
            uint4 u0 = *(const uint4*)&pss[r][q * 16];
            uint4 u1 = *(const uint4*)&pss[r][q * 16 + 4];
            uint4 u2 = *(const uint4*)&pss[r][q * 16 + 8];
            uint4 u3 = *(const uint4*)&pss[r][q * 16 + 12];
            s[0]=__uint_as_float(u0.x); s[1]=__uint_as_float(u0.y); s[2]=__uint_as_float(u0.z); s[3]=__uint_as_float(u0.w);
            s[4]=__uint_as_float(u1.x); s[5]=__uint_as_float(u1.y); s[6]=__uint_as_float(u1.z); s[7]=__uint_as_float(u1.w);
            s[8]=__uint_as_float(u2.x); s[9]=__uint_as_float(u2.y); s[10]=__uint_as_float(u2.z); s[11]=__uint_as_float(u2.w);
            s[12]=__uint_as_float(u3.x); s[13]=__uint_as_float(u3.y); s[14]=__uint_as_float(u3.z); s[15]=__uint_as_float(u3.w);
            float lmax = s[0];
            #pragma unroll
            for (int i = 1; i < 16; ++i) lmax = fmaxf(lmax, s[i]);
            lmax = fmaxf(lmax, __shfl_xor(lmax, 1));
            lmax = fmaxf(lmax, __shfl_xor(lmax, 2));
            float mnew = fmaxf(m_run, lmax);
            float corr = expf(m_run - mnew);
            float p[16], rsum = 0.f;
            #pragma unroll
            for (int i = 0; i < 16; ++i) { p[i] = expf(s[i] - mnew); rsum += p[i]; }
            rsum += __shfl_xor(rsum, 1);
            rsum += __shfl_xor(rsum, 2);
            l_run = l_run * corr + rsum;
            m_run = mnew;
            if (q == 0) corr_s[r] = corr;
            #pragma unroll
            for (int i2 = 0; i2 < 8; ++i2) {
                float p0 = p[2 * i2], p1 = p[2 * i2 + 1];
                _Float16 h0 = (_Float16)p0, h1 = (_Float16)p1;
                _Float16 e0 = (_Float16)(p0 - (float)h0), e1 = (_Float16)(p1 - (float)h1);
                pss[r][q * 8 + i2]      = (unsigned int)hbits(h0) | ((unsigned int)hbits(h1) << 16);
                pss[r][32 + q * 8 + i2] = (unsigned int)hbits(e0) | ((unsigned int)hbits(e1) << 16);
            }
        }
        {
            const int r0 = (tid & 31) * 2, cb = (tid >> 5) * 4;
            #pragma unroll
            for (int ci = 0; ci < 2; ++ci) {
                int c0 = cb + 32 * ci;
                float4 v0 = *(const float4*)(vc + (size_t)(t * 64 + r0) * DH + c0);
                float4 v1 = *(const float4*)(vc + (size_t)(t * 64 + r0 + 1) * DH + c0);
                float a0[4] = {v0.x, v0.y, v0.z, v0.w};
                float a1[4] = {v1.x, v1.y, v1.z, v1.w};
                #pragma unroll
                for (int i = 0; i < 4; ++i) {
                    int c = c0 + i;
                    _Float16 h0 = (_Float16)a0[i], h1 = (_Float16)a1[i];
                    _Float16 e0 = (_Float16)(a0[i] - (float)h0), e1 = (_Float16)(a1[i] - (float)h1);
                    int off = c * 64 + (((r0 >> 3) ^ (c & 7)) << 3) + (r0 & 7);
                    *(unsigned int*)&kvh[off] = (unsigned int)hbits(h0) | ((unsigned int)hbits(h1) << 16);
                    *(unsigned int*)&kvl[off] = (unsigned int)hbits(e0) | ((unsigned int)hbits(e1) << 16);
                }
            }
        }
        __syncthreads();
        #pragma unroll
        for (int m = 0; m < 4; ++m)
            #pragma unroll
            for (int rg = 0; rg < 4; ++rg)
                acc_o[m][rg] *= corr_s[16 * m + lg * 4 + rg];
        #pragma unroll
        for (int ks = 0; ks < 2; ++ks) {
            int k0 = 32 * ks + (lg << 3);
            int dh = 16 * wv + ll;
            int boff = dh * 64 + (((k0 >> 3) ^ (dh & 7)) << 3);
            f16x8 vh8 = *(const f16x8*)&kvh[boff];
            f16x8 vl8 = *(const f16x8*)&kvl[boff];
            #pragma unroll
            for (int m = 0; m < 4; ++m) {
                int prow = 16 * m + ll;
                union { uint4 u; f16x8 f; } ph, pe;
                ph.u = *(const uint4*)&pss[prow][16 * ks + lg * 4];
                pe.u = *(const uint4*)&pss[prow][32 + 16 * ks + lg * 4];
                acc_o[m] = __builtin_amdgcn_mfma_f32_16x16x32_f16(ph.f, vh8, acc_o[m], 0, 0, 0);
                acc_o[m] = __builtin_amdgcn_mfma_f32_16x16x32_f16(ph.f, vl8, acc_o[m], 0, 0, 0);
                acc_o[m] = __builtin_amdgcn_mfma_f32_16x16x32_f16(pe.f, vh8, acc_o[m], 0, 0, 0);
            }
        }
    }
    const size_t base = ((size_t)bh * NCH + ch) * 64;
    #pragma unroll
    for (int m = 0; m < 4; ++m)
        #pragma unroll
        for (int rg = 0; rg < 4; ++rg) {
            int row = 16 * m + lg * 4 + rg;
            pacc[(base + row) * 64 + 16 * wv + ll] = acc_o[m][rg];
        }
    if ((tid & 3) == 0) {
        int r = tid >> 2;
        pm[base + r] = m_run;
        pl[base + r] = l_run;
    }
}

// ---------------- K5b: combine sim3 partials -> t3 ----------------
__global__ __launch_bounds__(256) void k_sim3comb(const float* __restrict__ pacc,
    const float* __restrict__ pm, const float* __restrict__ pl, float* __restrict__ t3)
{
    __shared__ float w[NCH][64];
    __shared__ float Linv[64];
    const int bh = blockIdx.x;
    const int tid = threadIdx.x;
    if (tid < 64) {
        float M = -INFINITY;
        for (int c = 0; c < NCH; ++c)
            M = fmaxf(M, pm[((size_t)bh * NCH + c) * 64 + tid]);
        float L = 0.f;
        for (int c = 0; c < NCH; ++c) {
            float e = expf(pm[((size_t)bh * NCH + c) * 64 + tid] - M);
            w[c][tid] = e;
            L = fmaf(e, pl[((size_t)bh * NCH + c) * 64 + tid], L);
        }
        Linv[tid] = 1.f / L;
    }
    __syncthreads();
    const int wv = tid >> 6, lane = tid & 63;
    for (int p = 0; p < 16; ++p) {
        int i = (p << 2) + wv;
        float o = 0.f;
        for (int c = 0; c < NCH; ++c)
            o = fmaf(w[c][i], pacc[(((size_t)bh * NCH + c) * 64 + i) * 64 + lane], o);
        t3[((size_t)bh * 64 + i) * 64 + lane] = o * Linv[i];
    }
}

// ---------------- K6: pinv (LDS-resident, 256 thr, 4x4 register tiles) + t2 = z @ t3 -----
__device__ __forceinline__ void mm64t(float* __restrict__ C, const float* A,
    const float* Bm, const float* S, float sa, float sm, int tid)
{
    const int ty = tid >> 4, tx = tid & 15;
    float r[4][4] = {};
    __syncthreads();
    #pragma unroll 4
    for (int k = 0; k < 64; ++k) {
        float4 b4 = *(const float4*)&Bm[(k << 6) + (tx << 2)];
        #pragma unroll
        for (int i = 0; i < 4; ++i) {
            float a = A[(((ty << 2) + i) << 6) + k];
            r[i][0] = fmaf(a, b4.x, r[i][0]);
            r[i][1] = fmaf(a, b4.y, r[i][1]);
            r[i][2] = fmaf(a, b4.z, r[i][2]);
            r[i][3] = fmaf(a, b4.w, r[i][3]);
        }
    }
    __syncthreads();
    #pragma unroll
    for (int i = 0; i < 4; ++i) {
        int e = (((ty << 2) + i) << 6) + (tx << 2);
        float4 v = make_float4(sm * r[i][0], sm * r[i][1], sm * r[i][2], sm * r[i][3]);
        if (S) {
            v.x = fmaf(sa, S[e], v.x);     v.y = fmaf(sa, S[e + 1], v.y);
            v.z = fmaf(sa, S[e + 2], v.z); v.w = fmaf(sa, S[e + 3], v.w);
        }
        *(float4*)&C[e] = v;
    }
    __syncthreads();
}

__device__ __forceinline__ void mm64gt(float* __restrict__ C, const float* __restrict__ Ag,
    const float* __restrict__ Bm, int tid)
{
    const int ty = tid >> 4, tx = tid & 15;
    float r[4][4] = {};
    __syncthreads();
    #pragma unroll 4
    for (int k = 0; k < 64; ++k) {
        float4 b4 = *(const float4*)&Bm[(k << 6) + (tx << 2)];
        #pragma unroll
        for (int i = 0; i < 4; ++i) {
            float a = Ag[(((ty << 2) + i) << 6) + k];
            r[i][0] = fmaf(a, b4.x, r[i][0]);
            r[i][1] = fmaf(a, b4.y, r[i][1]);
            r[i][2] = fmaf(a, b4.z, r[i][2]);
            r[i][3] = fmaf(a, b4.w, r[i][3]);
        }
    }
    __syncthreads();
    #pragma unroll
    for (int i = 0; i < 4; ++i) {
        int e = (((ty << 2) + i) << 6) + (tx << 2);
        *(float4*)&C[e] = make_float4(r[i][0], r[i][1], r[i][2], r[i][3]);
    }
    __syncthreads();
}

__global__ __launch_bounds__(256) void k_pinv(const float* __restrict__ attn2,
    const float* __restrict__ mx, const float* __restrict__ t3g, float* __restrict__ t2g)
{
    __shared__ float Zs[4096], Ab[4096], Db[4096];
    const int tid = threadIdx.x;
    const int bh = blockIdx.x;
    const float inv = 1.0f / (mx[0] * mx[1]);
    const float* a2 = attn2 + (size_t)bh * 4096;
    for (int e = tid; e < 4096; e += 256) {
        int i = e >> 6, j = e & 63;
        Zs[e] = a2[(j << 6) + i] * inv;
    }
    for (int it = 0; it < 6; ++it) {
        mm64gt(Ab, a2, Zs, tid);
        mm64t(Db, Ab, Ab, Ab, 7.f, -1.f, tid);
        for (int e = tid; e < 4096; e += 256) {
            int i = e >> 6, j = e & 63;
            Db[e] = ((i == j) ? 15.f : 0.f) - Db[e];
        }
        mm64t(Ab, Zs, Ab, nullptr, 0.f, 1.f, tid);
        mm64t(Zs, Ab, Db, Zs, 3.25f, -0.25f, tid);
    }
    for (int e = tid; e < 4096; e += 256) Ab[e] = t3g[(size_t)bh * 4096 + e];
    mm64t(Db, Zs, Ab, nullptr, 0.f, 1.f, tid);
    for (int e = tid; e < 4096; e += 256) t2g[(size_t)bh * 4096 + e] = Db[e];
}

// ---------------- K7: out1 = softmax(mq@k_l^T) @ t2  (MFMA, conv in k_conv) --------
__global__ __launch_bounds__(256) void k_attn1(const float* __restrict__ mq,
    const float* __restrict__ klg, const float* __restrict__ t2g,
    float* __restrict__ opre)
{
    __shared__ __align__(16) _Float16 klh[4096], kll[4096];
    __shared__ __align__(16) _Float16 t2h[4096], t2l[4096];
    __shared__ __align__(16) unsigned int qps[64 * 68];
    const int bh = blockIdx.x;
    const int b = bh >> 3, h = bh & 7;
    const int rgb = blockIdx.y;
    const int tid = threadIdx.x;
    const int wv = tid >> 6, lane = tid & 63;
    const int lg = lane >> 4, ll = lane & 15;

    _Float16* qh_ = (_Float16*)qps;
    _Float16* ql_ = qh_ + 4096;

    #pragma unroll
    for (int it = 0; it < 4; ++it) {
        int e = tid + 256 * it;
        int r = e >> 4, c0 = (e & 15) << 2;
        float4 kx = *(const float4*)(klg + (size_t)bh * 4096 + r * 64 + c0);
        f16x4 hh, lo;
        float vals[4] = {kx.x, kx.y, kx.z, kx.w};
        #pragma unroll
        for (int i = 0; i < 4; ++i) {
            _Float16 hv = (_Float16)vals[i];
            hh[i] = hv; lo[i] = (_Float16)(vals[i] - (float)hv);
        }
        int off = r * 64 + (((c0 >> 3) ^ (r & 7)) << 3) + (c0 & 7);
        *(f16x4*)&klh[off] = hh;
        *(f16x4*)&kll[off] = lo;
    }
    {
        const int r0 = (tid & 31) * 2, cb = (tid >> 5) * 4;
        #pragma unroll
        for (int ci = 0; ci < 2; ++ci) {
            int c0 = cb + 32 * ci;
            float4 v0 = *(const float4*)(t2g + (size_t)bh * 4096 + (size_t)r0 * 64 + c0);
            float4 v1 = *(const float4*)(t2g + (size_t)bh * 4096 + (size_t)(r0 + 1) * 64 + c0);
            float a0[4] = {v0.x, v0.y, v0.z, v0.w};
            float a1[4] = {v1.x, v1.y, v1.z, v1.w};
            #pragma unroll
            for (int i = 0; i < 4; ++i) {
                int c = c0 + i;
                _Float16 h0 = (_Float16)a0[i], h1 = (_Float16)a1[i];
                _Float16 e0 = (_Float16)(a0[i] - (float)h0), e1 = (_Float16)(a1[i] - (float)h1);
                int off = c * 64 + (((r0 >> 3) ^ (c & 7)) << 3) + (r0 & 7);
                *(unsigned int*)&t2h[off] = (unsigned int)hbits(h0) | ((unsigned int)hbits(h1) << 16);
                *(unsigned int*)&t2l[off] = (unsigned int)hbits(e0) | ((unsigned int)hbits(e1) << 16);
            }
        }
    }

    const float* mqb = mq + (size_t)bh * NP * DH;
    f16x8 bkh[2], bkl2[2], bth[2], btl2[2];

    for (int t = 0; t < 8; ++t) {
        const int row0 = (rgb << 9) + (t << 6);
        #pragma unroll
        for (int it = 0; it < 4; ++it) {
            int e = tid + 256 * it;
            int r = e >> 4, c0 = (e & 15) << 2;
            float4 qv = *(const float4*)(mqb + (size_t)(row0 + r) * DH + c0);
            f16x4 hh, lo;
            float vals[4] = {qv.x, qv.y, qv.z, qv.w};
            #pragma unroll
            for (int i = 0; i < 4; ++i) {
                _Float16 hv = (_Float16)vals[i];
                hh[i] = hv; lo[i] = (_Float16)(vals[i] - (float)hv);
            }
            int off = r * 64 + (((c0 >> 3) ^ (r & 7)) << 3) + (c0 & 7);
            *(f16x4*)&qh_[off] = hh;
            *(f16x4*)&ql_[off] = lo;
        }
        __syncthreads();
        if (t == 0) {
            #pragma unroll
            for (int ks = 0; ks < 2; ++ks) {
                int k0 = 32 * ks + (lg << 3);
                int br = 16 * wv + ll;
                int boff = br * 64 + (((k0 >> 3) ^ (br & 7)) << 3);
                bkh[ks]  = *(const f16x8*)&klh[boff];
                bkl2[ks] = *(const f16x8*)&kll[boff];
                bth[ks]  = *(const f16x8*)&t2h[boff];
                btl2[ks] = *(const f16x8*)&t2l[boff];
            }
        }
        f16x8 ah[2][4], al[2][4];
        #pragma unroll
        for (int ks = 0; ks < 2; ++ks) {
            int k0 = 32 * ks + (lg << 3);
            #pragma unroll
            for (int m = 0; m < 4; ++m) {
                int arw = 16 * m + ll;
                int aoff = arw * 64 + (((k0 >> 3) ^ (arw & 7)) << 3);
                ah[ks][m] = *(const f16x8*)&qh_[aoff];
                al[ks][m] = *(const f16x8*)&ql_[aoff];
            }
        }
        __syncthreads();
        f32x4 accs[4] = {};
        #pragma unroll
        for (int ks = 0; ks < 2; ++ks)
            #pragma unroll
            for (int m = 0; m < 4; ++m) {
                accs[m] = __builtin_amdgcn_mfma_f32_16x16x32_f16(ah[ks][m], bkh[ks], accs[m], 0, 0, 0);
                accs[m] = __builtin_amdgcn_mfma_f32_16x16x32_f16(ah[ks][m], bkl2[ks], accs[m], 0, 0, 0);
                accs[m] = __builtin_amdgcn_mfma_f32_16x16x32_f16(al[ks][m], bkh[ks], accs[m], 0, 0, 0);
            }
        #pragma unroll
        for (int m = 0; m < 4; ++m)
            #pragma unroll
            for (int rgi = 0; rgi < 4; ++rgi)
                qps[(16 * m + lg * 4 + rgi) * 68 + 16 * wv + ll] = __float_as_uint(accs[m][rgi]);
        __syncthreads();
        {
            const int r = tid >> 2, q4 = tid & 3;
            float s[16];
            #pragma unroll
            for (int j = 0; j < 16; ++j) s[j] = __uint_as_float(qps[r * 68 + q4 * 16 + j]);
            float rmax = s[0];
            #pragma unroll
            for (int j = 1; j < 16; ++j) rmax = fmaxf(rmax, s[j]);
            rmax = fmaxf(rmax, __shfl_xor(rmax, 1));
            rmax = fmaxf(rmax, __shfl_xor(rmax, 2));
            float p[16], rsum = 0.f;
            #pragma unroll
            for (int j = 0; j < 16; ++j) { p[j] = expf(s[j] - rmax); rsum += p[j]; }
            rsum += __shfl_xor(rsum, 1);
            rsum += __shfl_xor(rsum, 2);
            float rinv = 1.f / rsum;
            #pragma unroll
            for (int j = 0; j < 16; ++j) p[j] *= rinv;
            #pragma unroll
            for (int i2 = 0; i2 < 8; ++i2) {
                float p0 = p[2 * i2], p1 = p[2 * i2 + 1];
                _Float16 h0 = (_Float16)p0, h1 = (_Float16)p1;
                _Float16 e0 = (_Float16)(p0 - (float)h0), e1 = (_Float16)(p1 - (float)h1);
                qps[r * 68 + q4 * 8 + i2]      = (unsigned int)hbits(h0) | ((unsigned int)hbits(h1) << 16);
                qps[r * 68 + 32 + q4 * 8 + i2] = (unsigned int)hbits(e0) | ((unsigned int)hbits(e1) << 16);
            }
        }
        __syncthreads();
        f32x4 acco[4] = {};
        #pragma unroll
        for (int ks = 0; ks < 2; ++ks)
            #pragma unroll
            for (int m = 0; m < 4; ++m) {
                int prow = 16 * m + ll;
                union { uint4 u; f16x8 f; } ph, pe;
                ph.u = *(const uint4*)&qps[prow * 68 + 16 * ks + lg * 4];
                pe.u = *(const uint4*)&qps[prow * 68 + 32 + 16 * ks + lg * 4];
                acco[m] = __builtin_amdgcn_mfma_f32_16x16x32_f16(ph.f, bth[ks], acco[m], 0, 0, 0);
                acco[m] = __builtin_amdgcn_mfma_f32_16x16x32_f16(ph.f, btl2[ks], acco[m], 0, 0, 0);
                acco[m] = __builtin_amdgcn_mfma_f32_16x16x32_f16(pe.f, bth[ks], acco[m], 0, 0, 0);
            }
        {
            int col = 16 * wv + ll;
            #pragma unroll
            for (int m = 0; m < 4; ++m) {
                int rb = row0 + 16 * m + lg * 4;
                #pragma unroll
                for (int rgi = 0; rgi < 4; ++rgi)
                    opre[((size_t)b * NP + rb + rgi) * DIM + h * DH + col] = acco[m][rgi];
            }
        }
        __syncthreads();
    }
}

// ---------------- K7b: opre += depthwise conv(v)  (LDS-staged sliding window) ------------
__global__ __launch_bounds__(256) void k_conv(const float* __restrict__ vb,
    const float* __restrict__ cwg, float* __restrict__ opre)
{
    __shared__ float vs[96][68];
    __shared__ float cw[33];
    const int bh = blockIdx.x;
    const int b = bh >> 3, h = bh & 7;
    const int row0 = blockIdx.y << 6;
    const int tid = threadIdx.x;
    const float* vbase = vb + (size_t)bh * NTOT * DH;
    #pragma unroll
    for (int it = 0; it < 6; ++it) {
        int e = tid + 256 * it;
        int r = e >> 4, c4 = (e & 15) << 2;
        int gr = row0 - 16 + r;
        float4 v = (gr >= 0) ? *(const float4*)(vbase + (size_t)gr * DH + c4)
                             : make_float4(0.f, 0.f, 0.f, 0.f);
        *(float4*)&vs[r][c4] = v;
    }
    if (tid < 33) cw[tid] = cwg[h * 33 + tid];
    __syncthreads();
    const int ty = tid >> 4, c4 = (tid & 15) << 2;
    #pragma unroll
    for (int i = 0; i < 4; ++i) {
        int lr = ty * 4 + i;
        float4 a = make_float4(0.f, 0.f, 0.f, 0.f);
        #pragma unroll 33
        for (int k = 0; k < 33; ++k) {
            float w = cw[k];
            const float* p = &vs[lr + k][c4];
            a.x = fmaf(w, p[0], a.x); a.y = fmaf(w, p[1], a.y);
            a.z = fmaf(w, p[2], a.z); a.w = fmaf(w, p[3], a.w);
        }
        float* op = opre + ((size_t)b * NP + row0 + lr) * DIM + h * DH + c4;
        float4 o = *(const float4*)op;
        o.x += a.x; o.y += a.y; o.z += a.z; o.w += a.w;
        *(float4*)op = o;
    }
}

extern "C" void kernel_launch(void* const* d_in, const int* in_sizes, int n_in,
                              void* d_out, int out_size, void* d_ws, size_t ws_size,
                              hipStream_t stream)
{
    const float* x   = (const float*)d_in[0];
    const float* ps  = (const float*)d_in[1];
    const float* wq  = (const float*)d_in[2];
    const float* wo  = (const float*)d_in[3];
    const float* cwg = (const float*)d_in[4];
    float* out = (float*)d_out;
    float* ws  = (float*)d_ws;

    float* mq   = out;               // d_out doubles as mq scratch; k_gemm<1> overwrites last
    float* kb   = ws + OFF_K;
    float* vb   = ws + OFF_V;
    float* ql   = ws + OFF_QL;
    float* kl   = ws + OFF_KL;
    float* a2   = ws + OFF_A2;
    float* t3   = ws + OFF_T3;
    float* t2   = ws + OFF_T2;
    float* mx   = ws + OFF_MAX;
    float* opre = ws + OFF_OPRE;
    float* pacc = opre;
    float* pm   = opre + 3145728ull;
    float* pl   = pm + 49152ull;
    _Float16* BTqh = (_Float16*)(ws + OFF_QL);
    _Float16* BTql = BTqh + 1536 * 512;
    _Float16* BToh = (_Float16*)(ws + OFF_K);
    _Float16* BTol = BToh + 512 * 512;

    k_cvtw        <<<dim3(24, 8), 256, 0, stream>>>(wq, BTqh, BTql, 512, 1536);
    k_gemm_split<0><<<4608, 256, 0, stream>>>(x, ps, BTqh, BTql, mq, kb, vb);
    k_land        <<<4096, 256, 0, stream>>>(mq, kb, ql, kl);
    k_sim2        <<<32, 256, 0, stream>>>(ql, kl, a2, mx);
    k_maxes       <<<32, 64, 0, stream>>>(a2, mx);
    k_sim3part    <<<dim3(32, NCH), 256, 0, stream>>>(ql, kb, vb, pacc, pm, pl);
    k_sim3comb    <<<32, 256, 0, stream>>>(pacc, pm, pl, t3);
    k_cvtw        <<<dim3(8, 8), 256, 0, stream>>>(wo, BToh, BTol, 512, 512);
    k_pinv        <<<32, 256, 0, stream>>>(a2, mx, t3, t2);
    k_attn1       <<<dim3(32, 8), 256, 0, stream>>>(mq, kl, t2, opre);
    k_conv        <<<dim3(32, 64), 256, 0, stream>>>(vb, cwg, opre);
    k_gemm_split<1><<<512, 256, 0, stream>>>(opre, nullptr, BToh, BTol, out, nullptr, nullptr);
}

// Round 12
// 583.186 us; speedup vs baseline: 1.2781x; 1.2781x over previous
//
#include <hip/hip_runtime.h>
#include <math.h>

#define Bb 4
#define Hh 8
#define NP 4096
#define PTOT 8192
#define NTOT 12288
#define DIM 512
#define DH 64
#define SCALE 0.125f
#define NCH 24
#define CHUNK 512

typedef __attribute__((ext_vector_type(8))) _Float16 f16x8;
typedef __attribute__((ext_vector_type(4))) _Float16 f16x4;
typedef __attribute__((ext_vector_type(4))) float f32x4;

// ---------------- workspace layout (float offsets) ----------------
#define SZ_K    (4ull*8*12288*64)      // 25,165,824
#define SZ_L    (32ull*64*64)          // 131,072
#define OFF_K    0ull
#define OFF_V    (OFF_K + SZ_K)
#define OFF_QL   (OFF_V + SZ_K)
#define OFF_KL   (OFF_QL + SZ_L)
#define OFF_A2   (OFF_KL + SZ_L)
#define OFF_T3   (OFF_A2 + SZ_L)
#define OFF_T2   (OFF_T3 + SZ_L)
#define OFF_MAX  (OFF_T2 + SZ_L)
#define OFF_OPRE (OFF_MAX + 16ull)
// total = 59,375,648 floats (237.5 MB) — proven fit.
// BTq aliases [OFF_QL...), BTo aliases kb (dead after k_sim3part).

__device__ __forceinline__ unsigned short hbits(_Float16 x) {
    union { _Float16 f; unsigned short u; } c; c.f = x; return c.u;
}

// ---------------- transpose + fp16-split weights: w[K][N] -> BT[N][K] hi/lo ----------------
// (round-8 proven version: row-major BT, consumed via LDS staging in k_gemm_split)
__global__ __launch_bounds__(256) void k_cvtw(const float* __restrict__ w,
    _Float16* __restrict__ bh, _Float16* __restrict__ bl, int K, int N)
{
    __shared__ float t[64][65];
    const int n0 = blockIdx.x * 64, k0 = blockIdx.y * 64;
    const int tid = threadIdx.x;
    #pragma unroll
    for (int i = 0; i < 4; ++i) {
        int r = (tid >> 4) + i * 16;
        int c = (tid & 15) * 4;
        float4 v = *(const float4*)(w + (size_t)(k0 + r) * N + n0 + c);
        t[r][c] = v.x; t[r][c+1] = v.y; t[r][c+2] = v.z; t[r][c+3] = v.w;
    }
    __syncthreads();
    const int n = tid >> 2, kq = (tid & 3) * 16;
    f16x8 h8[2], l8[2];
    #pragma unroll
    for (int j = 0; j < 16; ++j) {
        float a = t[kq + j][n];
        _Float16 hh = (_Float16)a;
        _Float16 ll = (_Float16)(a - (float)hh);
        h8[j >> 3][j & 7] = hh;
        l8[j >> 3][j & 7] = ll;
    }
    size_t o = (size_t)(n0 + n) * K + k0 + kq;
    *(f16x8*)(bh + o) = h8[0]; *(f16x8*)(bh + o + 8) = h8[1];
    *(f16x8*)(bl + o) = l8[0]; *(f16x8*)(bl + o + 8) = l8[1];
}

// ---------------- fp16-split MFMA GEMM, 2-phase dbuf, depth-2 prefetch, XCD swizzle ------
// (round-8 proven version: 303 µs, MfmaUtil 35%, VGPR 112 — stays under the 128-VGPR cliff)
__device__ __forceinline__ int hoff(int r, int slot) {
    return r * 32 + (((slot ^ (r >> 1)) & 3) << 3);
}

template<int MODE>
__global__ __launch_bounds__(256) void k_gemm_split(
    const float* __restrict__ Asrc0, const float* __restrict__ Asrc1,
    const _Float16* __restrict__ BTh, const _Float16* __restrict__ BTl,
    float* __restrict__ out0, float* __restrict__ out1, float* __restrict__ out2)
{
    __shared__ __align__(16) _Float16 Ah[2][128 * 32], Al[2][128 * 32];
    __shared__ __align__(16) _Float16 Bh[2][128 * 32], Bl[2][128 * 32];
    const int NB = (MODE == 0) ? 12 : 4;
    const int id = blockIdx.x;
    const int w8 = id % (NB * 8);
    const int n0 = (w8 >> 3) * 128;
    const int m0 = ((id / (NB * 8)) * 8 + (w8 & 7)) * 128;
    const int tid = threadIdx.x;
    const int wv = tid >> 6, lane = tid & 63;
    const int wr = wv >> 1, wc = wv & 1;
    const int kslot = lane >> 4;

    int ar[2], asl[2];
    const float* aptr[2];
    #pragma unroll
    for (int i = 0; i < 2; ++i) {
        int id2 = tid + 256 * i;
        ar[i] = id2 >> 2; asl[i] = id2 & 3;
        int grow = m0 + ar[i];
        if (MODE == 0) {
            int bi = grow / NTOT;
            int pos = grow - bi * NTOT;
            aptr[i] = (pos < NP) ? (Asrc0 + ((size_t)bi * NP + pos) * DIM)
                                 : (Asrc1 + ((size_t)bi * PTOT + (pos - NP)) * DIM);
        } else {
            aptr[i] = Asrc0 + (size_t)grow * DIM;
        }
    }

    float4 a0[2], a1[2];
    f16x8 vbh[2], vbl[2];

    auto LOADT = [&](int k0) {
        #pragma unroll
        for (int i = 0; i < 2; ++i) {
            a0[i] = *(const float4*)(aptr[i] + k0 + asl[i] * 8);
            a1[i] = *(const float4*)(aptr[i] + k0 + asl[i] * 8 + 4);
            size_t bo = (size_t)(n0 + ar[i]) * DIM + k0 + asl[i] * 8;
            vbh[i] = *(const f16x8*)(BTh + bo);
            vbl[i] = *(const f16x8*)(BTl + bo);
        }
    };
    auto WRITET = [&](int buf) {
        #pragma unroll
        for (int i = 0; i < 2; ++i) {
            f16x8 h, l;
            float vals[8] = {a0[i].x, a0[i].y, a0[i].z, a0[i].w,
                             a1[i].x, a1[i].y, a1[i].z, a1[i].w};
            #pragma unroll
            for (int j = 0; j < 8; ++j) {
                _Float16 hh = (_Float16)vals[j];
                h[j] = hh;
                l[j] = (_Float16)(vals[j] - (float)hh);
            }
            int o = hoff(ar[i], asl[i]);
            *(f16x8*)&Ah[buf][o] = h;
            *(f16x8*)&Al[buf][o] = l;
            *(f16x8*)&Bh[buf][o] = vbh[i];
            *(f16x8*)&Bl[buf][o] = vbl[i];
        }
    };

    LOADT(0);
    WRITET(0);
    LOADT(32);
    int cur = 0;

    f32x4 acc[4][4] = {};
    for (int t = 0; t < 16; ++t) {
        __syncthreads();
        f16x8 afh[4], afl[4];
        #pragma unroll
        for (int m = 0; m < 4; ++m) {
            int o = hoff(wr * 64 + m * 16 + (lane & 15), kslot);
            afh[m] = *(const f16x8*)&Ah[cur][o];
            afl[m] = *(const f16x8*)&Al[cur][o];
        }
        f16x8 bfh[4], bfl[4];
        #pragma unroll
        for (int n = 0; n < 4; ++n) {
            int o = hoff(wc * 64 + n * 16 + (lane & 15), kslot);
            bfh[n] = *(const f16x8*)&Bh[cur][o];
            bfl[n] = *(const f16x8*)&Bl[cur][o];
        }
        if (t < 15) WRITET(cur ^ 1);
        if (t < 14) LOADT((t + 2) * 32);
        #pragma unroll
        for (int n = 0; n < 4; ++n)
            #pragma unroll
            for (int m = 0; m < 4; ++m) {
                acc[m][n] = __builtin_amdgcn_mfma_f32_16x16x32_f16(afh[m], bfh[n], acc[m][n], 0, 0, 0);
                acc[m][n] = __builtin_amdgcn_mfma_f32_16x16x32_f16(afh[m], bfl[n], acc[m][n], 0, 0, 0);
                acc[m][n] = __builtin_amdgcn_mfma_f32_16x16x32_f16(afl[m], bfh[n], acc[m][n], 0, 0, 0);
            }
        cur ^= 1;
    }
    #pragma unroll
    for (int m = 0; m < 4; ++m) {
        #pragma unroll
        for (int n = 0; n < 4; ++n) {
            int gcol = n0 + wc * 64 + n * 16 + (lane & 15);
            int rbase = m0 + wr * 64 + m * 16 + (lane >> 4) * 4;
            if (MODE == 1) {
                #pragma unroll
                for (int r = 0; r < 4; ++r)
                    out0[(size_t)(rbase + r) * DIM + gcol] = acc[m][n][r];
            } else {
                int which = gcol >> 9, h = (gcol >> 6) & 7, d = gcol & 63;
                #pragma unroll
                for (int r = 0; r < 4; ++r) {
                    int row = rbase + r;
                    int bi = row / NTOT;
                    int p = row - bi * NTOT;
                    float v = acc[m][n][r];
                    if (which == 0) {
                        if (p < NP) out0[(((size_t)bi * Hh + h) * NP + p) * DH + d] = v * SCALE;
                    } else if (which == 1) {
                        out1[(((size_t)bi * Hh + h) * NTOT + p) * DH + d] = v;
                    } else {
                        out2[(((size_t)bi * Hh + h) * NTOT + p) * DH + d] = v;
                    }
                }
            }
        }
    }
}

// ---------------- K2: landmark means (vectorized) ----------------
__global__ __launch_bounds__(256) void k_land(const float* __restrict__ mq,
    const float* __restrict__ kb, float* __restrict__ ql, float* __restrict__ kl)
{
    __shared__ float part[16][64];
    int idx = blockIdx.x;
    const int tid = threadIdx.x;
    const int rg = tid >> 4, c4 = (tid & 15) << 2;
    const float* src;
    float* dst;
    int R; float sc;
    if (idx < 2048) {
        int bh = idx >> 6, i = idx & 63;
        src = mq + ((size_t)bh * NP + i * 64) * DH;
        dst = ql + ((size_t)bh * 64 + i) * 64;
        R = 64; sc = 1.f / 64.f;
    } else {
        idx -= 2048;
        int bh = idx >> 6, i = idx & 63;
        src = kb + ((size_t)bh * NTOT + i * 192) * DH;
        dst = kl + ((size_t)bh * 64 + i) * 64;
        R = 192; sc = 1.f / 192.f;
    }
    float4 a = make_float4(0.f, 0.f, 0.f, 0.f);
    for (int r = rg; r < R; r += 16) {
        float4 v = *(const float4*)(src + (size_t)r * DH + c4);
        a.x += v.x; a.y += v.y; a.z += v.z; a.w += v.w;
    }
    *(float4*)&part[rg][c4] = a;
    __syncthreads();
    if (tid < 64) {
        float s = 0.f;
        #pragma unroll
        for (int g = 0; g < 16; ++g) s += part[g][tid];
        dst[tid] = s * sc;
    }
}

// ---------------- K3: attn2 = softmax(q_l @ k_l^T); also zero-inits mx ----------------
__global__ __launch_bounds__(256) void k_sim2(const float* __restrict__ ql,
    const float* __restrict__ kl, float* __restrict__ a2, float* __restrict__ mx)
{
    __shared__ float qs[64][64];
    __shared__ float ks[64][65];
    __shared__ float S[64][65];
    const int tid = threadIdx.x;
    const int bh = blockIdx.x;
    if (bh == 0 && tid < 2) mx[tid] = 0.f;
    for (int e = tid; e < 4096; e += 256) {
        qs[e >> 6][e & 63] = ql[(size_t)bh * 4096 + e];
        ks[e >> 6][e & 63] = kl[(size_t)bh * 4096 + e];
    }
    __syncthreads();
    for (int sI = 0; sI < 16; ++sI) {
        int e = (sI << 8) + tid;
        int i = e >> 6, j = e & 63;
        float acc = 0.f;
        #pragma unroll 16
        for (int d = 0; d < 64; ++d) acc = fmaf(qs[i][d], ks[j][d], acc);
        S[i][j] = acc;
    }
    __syncthreads();
    const int wv = tid >> 6, lane = tid & 63;
    for (int i = wv; i < 64; i += 4) {
        float v = S[i][lane];
        float mxv = v;
        #pragma unroll
        for (int off = 32; off; off >>= 1) mxv = fmaxf(mxv, __shfl_xor(mxv, off));
        float p = expf(v - mxv);
        float sm = p;
        #pragma unroll
        for (int off = 32; off; off >>= 1) sm += __shfl_xor(sm, off);
        a2[((size_t)bh * 64 + i) * 64 + lane] = p / sm;
    }
}

// ---------------- K4: global max of row/col abs-sums of attn2 ----------------
__global__ __launch_bounds__(64) void k_maxes(const float* __restrict__ a2,
    float* __restrict__ mx)
{
    const int bh = blockIdx.x;
    const int i = threadIdx.x;
    const float* base = a2 + (size_t)bh * 4096;
    float cs = 0.f, rs = 0.f;
    for (int j = 0; j < 64; ++j) {
        cs += fabsf(base[i * 64 + j]);
        rs += fabsf(base[j * 64 + i]);
    }
    #pragma unroll
    for (int off = 32; off; off >>= 1) {
        cs = fmaxf(cs, __shfl_xor(cs, off));
        rs = fmaxf(rs, __shfl_xor(rs, off));
    }
    if (i == 0) {
        atomicMax((unsigned int*)&mx[0], __float_as_uint(cs));
        atomicMax((unsigned int*)&mx[1], __float_as_uint(rs));
    }
}

// ---------------- K5a: sim3 partials — fp16-split MFMA flash over a 512-row chunk ----------
__global__ __launch_bounds__(256) void k_sim3part(const float* __restrict__ qlg,
    const float* __restrict__ kb, const float* __restrict__ vb,
    float* __restrict__ pacc, float* __restrict__ pm, float* __restrict__ pl)
{
    __shared__ __align__(16) _Float16 qsh[4096], qsl[4096];
    __shared__ __align__(16) _Float16 kvh[4096], kvl[4096];
    __shared__ __align__(16) unsigned int pss[64][68];
    __shared__ float corr_s[64];
    const int bh = blockIdx.x, ch = blockIdx.y;
    const int tid = threadIdx.x;
    const int wv = tid >> 6, lane = tid & 63;
    const int lg = lane >> 4, ll = lane & 15;

    #pragma unroll
    for (int it = 0; it < 4; ++it) {
        int e = tid + 256 * it;
        int r = e >> 4, c0 = (e & 15) << 2;
        float4 qv = *(const float4*)(qlg + (size_t)bh * 4096 + r * 64 + c0);
        f16x4 h, l;
        float vals[4] = {qv.x, qv.y, qv.z, qv.w};
        #pragma unroll
        for (int i = 0; i < 4; ++i) {
            _Float16 hh = (_Float16)vals[i];
            h[i] = hh; l[i] = (_Float16)(vals[i] - (float)hh);
        }
        int off = r * 64 + (((c0 >> 3) ^ (r & 7)) << 3) + (c0 & 7);
        *(f16x4*)&qsh[off] = h;
        *(f16x4*)&qsl[off] = l;
    }

    const float* kc = kb + ((size_t)bh * NTOT + ch * CHUNK) * DH;
    const float* vc = vb + ((size_t)bh * NTOT + ch * CHUNK) * DH;

    float m_run = -INFINITY, l_run = 0.f;
    f32x4 acc_o[4] = {};

    for (int t = 0; t < CHUNK / 64; ++t) {
        __syncthreads();
        #pragma unroll
        for (int it = 0; it < 4; ++it) {
            int e = tid + 256 * it;
            int r = e >> 4, c0 = (e & 15) << 2;
            float4 kx = *(const float4*)(kc + (size_t)(t * 64 + r) * DH + c0);
            f16x4 h, l;
            float vals[4] = {kx.x, kx.y, kx.z, kx.w};
            #pragma unroll
            for (int i = 0; i < 4; ++i) {
                _Float16 hh = (_Float16)vals[i];
                h[i] = hh; l[i] = (_Float16)(vals[i] - (float)hh);
            }
            int off = r * 64 + (((c0 >> 3) ^ (r & 7)) << 3) + (c0 & 7);
            *(f16x4*)&kvh[off] = h;
            *(f16x4*)&kvl[off] = l;
        }
        __syncthreads();
        f32x4 accs[4] = {};
        #pragma unroll
        for (int ks = 0; ks < 2; ++ks) {
            int k0 = 32 * ks + (lg << 3);
            int brow = 16 * wv + ll;
            int boff = brow * 64 + (((k0 >> 3) ^ (brow & 7)) << 3);
            f16x8 bh8 = *(const f16x8*)&kvh[boff];
            f16x8 bl8 = *(const f16x8*)&kvl[boff];
            #pragma unroll
            for (int m = 0; m < 4; ++m) {
                int arow = 16 * m + ll;
                int aoff = arow * 64 + (((k0 >> 3) ^ (arow & 7)) << 3);
                f16x8 ah8 = *(const f16x8*)&qsh[aoff];
                f16x8 al8 = *(const f16x8*)&qsl[aoff];
                accs[m] = __builtin_amdgcn_mfma_f32_16x16x32_f16(ah8, bh8, accs[m], 0, 0, 0);
                accs[m] = __builtin_amdgcn_mfma_f32_16x16x32_f16(ah8, bl8, accs[m], 0, 0, 0);
                accs[m] = __builtin_amdgcn_mfma_f32_16x16x32_f16(al8, bh8, accs[m], 0, 0, 0);
            }
        }
        #pragma unroll
        for (int m = 0; m < 4; ++m)
            #pragma unroll
            for (int rg = 0; rg < 4; ++rg)
                pss[16 * m + lg * 4 + rg][16 * wv + ll] = __float_as_uint(accs[m][rg]);
        __syncthreads();
        {
            const int r = tid >> 2, q = tid & 3;
            float s[16];
            uint4 u0 = *(const uint4*)&pss[r][q * 16];
            uint4 u1 = *(const uint4*)&pss[r][q * 16 + 4];
            uint4 u2 = *(const uint4*)&pss[r][q * 16 + 8];
            uint4 u3 = *(const uint4*)&pss[r][q * 16 + 12];
            s[0]=__uint_as_float(u0.x); s[1]=__uint_as_float(u0.y); s[2]=__uint_as_float(u0.z); s[3]=__uint_as_float(u0.w);
            s[4]=__uint_as_float(u1.x); s[5]=__uint_as_float(u1.y); s[6]=__uint_as_float(u1.z); s[7]=__uint_as_float(u1.w);
            s[8]=__uint_as_float(u2.x); s[9]=__uint_as_float(u2.y); s[10]=__uint_as_float(u2.z); s[11]=__uint_as_float(u2.w);
            s[12]=__uint_as_float(u3.x); s[13]=__uint_as_float(u3.y); s[14]=__uint_as_float(u3.z); s[15]=__uint_as_float(u3.w);
            float lmax = s[0];
            #pragma unroll
            for (int i = 1; i < 16; ++i) lmax = fmaxf(lmax, s[i]);
            lmax = fmaxf(lmax, __shfl_xor(lmax, 1));
            lmax = fmaxf(lmax, __shfl_xor(lmax, 2));
            float mnew = fmaxf(m_run, lmax);
            float corr = expf(m_run - mnew);
            float p[16], rsum = 0.f;
            #pragma unroll
            for (int i = 0; i < 16; ++i) { p[i] = expf(s[i] - mnew); rsum += p[i]; }
            rsum += __shfl_xor(rsum, 1);
            rsum += __shfl_xor(rsum, 2);
            l_run = l_run * corr + rsum;
            m_run = mnew;
            if (q == 0) corr_s[r] = corr;
            #pragma unroll
            for (int i2 = 0; i2 < 8; ++i2) {
                float p0 = p[2 * i2], p1 = p[2 * i2 + 1];
                _Float16 h0 = (_Float16)p0, h1 = (_Float16)p1;
                _Float16 e0 = (_Float16)(p0 - (float)h0), e1 = (_Float16)(p1 - (float)h1);
                pss[r][q * 8 + i2]      = (unsigned int)hbits(h0) | ((unsigned int)hbits(h1) << 16);
                pss[r][32 + q * 8 + i2] = (unsigned int)hbits(e0) | ((unsigned int)hbits(e1) << 16);
            }
        }
        {
            const int r0 = (tid & 31) * 2, cb = (tid >> 5) * 4;
            #pragma unroll
            for (int ci = 0; ci < 2; ++ci) {
                int c0 = cb + 32 * ci;
                float4 v0 = *(const float4*)(vc + (size_t)(t * 64 + r0) * DH + c0);
                float4 v1 = *(const float4*)(vc + (size_t)(t * 64 + r0 + 1) * DH + c0);
                float a0[4] = {v0.x, v0.y, v0.z, v0.w};
                float a1[4] = {v1.x, v1.y, v1.z, v1.w};
                #pragma unroll
                for (int i = 0; i < 4; ++i) {
                    int c = c0 + i;
                    _Float16 h0 = (_Float16)a0[i], h1 = (_Float16)a1[i];
                    _Float16 e0 = (_Float16)(a0[i] - (float)h0), e1 = (_Float16)(a1[i] - (float)h1);
                    int off = c * 64 + (((r0 >> 3) ^ (c & 7)) << 3) + (r0 & 7);
                    *(unsigned int*)&kvh[off] = (unsigned int)hbits(h0) | ((unsigned int)hbits(h1) << 16);
                    *(unsigned int*)&kvl[off] = (unsigned int)hbits(e0) | ((unsigned int)hbits(e1) << 16);
                }
            }
        }
        __syncthreads();
        #pragma unroll
        for (int m = 0; m < 4; ++m)
            #pragma unroll
            for (int rg = 0; rg < 4; ++rg)
                acc_o[m][rg] *= corr_s[16 * m + lg * 4 + rg];
        #pragma unroll
        for (int ks = 0; ks < 2; ++ks) {
            int k0 = 32 * ks + (lg << 3);
            int dh = 16 * wv + ll;
            int boff = dh * 64 + (((k0 >> 3) ^ (dh & 7)) << 3);
            f16x8 vh8 = *(const f16x8*)&kvh[boff];
            f16x8 vl8 = *(const f16x8*)&kvl[boff];
            #pragma unroll
            for (int m = 0; m < 4; ++m) {
                int prow = 16 * m + ll;
                union { uint4 u; f16x8 f; } ph, pe;
                ph.u = *(const uint4*)&pss[prow][16 * ks + lg * 4];
                pe.u = *(const uint4*)&pss[prow][32 + 16 * ks + lg * 4];
                acc_o[m] = __builtin_amdgcn_mfma_f32_16x16x32_f16(ph.f, vh8, acc_o[m], 0, 0, 0);
                acc_o[m] = __builtin_amdgcn_mfma_f32_16x16x32_f16(ph.f, vl8, acc_o[m], 0, 0, 0);
                acc_o[m] = __builtin_amdgcn_mfma_f32_16x16x32_f16(pe.f, vh8, acc_o[m], 0, 0, 0);
            }
        }
    }
    const size_t base = ((size_t)bh * NCH + ch) * 64;
    #pragma unroll
    for (int m = 0; m < 4; ++m)
        #pragma unroll
        for (int rg = 0; rg < 4; ++rg) {
            int row = 16 * m + lg * 4 + rg;
            pacc[(base + row) * 64 + 16 * wv + ll] = acc_o[m][rg];
        }
    if ((tid & 3) == 0) {
        int r = tid >> 2;
        pm[base + r] = m_run;
        pl[base + r] = l_run;
    }
}

// ---------------- K5b: combine sim3 partials -> t3 ----------------
__global__ __launch_bounds__(256) void k_sim3comb(const float* __restrict__ pacc,
    const float* __restrict__ pm, const float* __restrict__ pl, float* __restrict__ t3)
{
    __shared__ float w[NCH][64];
    __shared__ float Linv[64];
    const int bh = blockIdx.x;
    const int tid = threadIdx.x;
    if (tid < 64) {
        float M = -INFINITY;
        for (int c = 0; c < NCH; ++c)
            M = fmaxf(M, pm[((size_t)bh * NCH + c) * 64 + tid]);
        float L = 0.f;
        for (int c = 0; c < NCH; ++c) {
            float e = expf(pm[((size_t)bh * NCH + c) * 64 + tid] - M);
            w[c][tid] = e;
            L = fmaf(e, pl[((size_t)bh * NCH + c) * 64 + tid], L);
        }
        Linv[tid] = 1.f / L;
    }
    __syncthreads();
    const int wv = tid >> 6, lane = tid & 63;
    for (int p = 0; p < 16; ++p) {
        int i = (p << 2) + wv;
        float o = 0.f;
        for (int c = 0; c < NCH; ++c)
            o = fmaf(w[c][i], pacc[(((size_t)bh * NCH + c) * 64 + i) * 64 + lane], o);
        t3[((size_t)bh * 64 + i) * 64 + lane] = o * Linv[i];
    }
}

// ---------------- K6: pinv (LDS-resident, 256 thr, 4x4 register tiles) + t2 = z @ t3 -----
__device__ __forceinline__ void mm64t(float* __restrict__ C, const float* A,
    const float* Bm, const float* S, float sa, float sm, int tid)
{
    const int ty = tid >> 4, tx = tid & 15;
    float r[4][4] = {};
    __syncthreads();
    #pragma unroll 4
    for (int k = 0; k < 64; ++k) {
        float4 b4 = *(const float4*)&Bm[(k << 6) + (tx << 2)];
        #pragma unroll
        for (int i = 0; i < 4; ++i) {
            float a = A[(((ty << 2) + i) << 6) + k];
            r[i][0] = fmaf(a, b4.x, r[i][0]);
            r[i][1] = fmaf(a, b4.y, r[i][1]);
            r[i][2] = fmaf(a, b4.z, r[i][2]);
            r[i][3] = fmaf(a, b4.w, r[i][3]);
        }
    }
    __syncthreads();
    #pragma unroll
    for (int i = 0; i < 4; ++i) {
        int e = (((ty << 2) + i) << 6) + (tx << 2);
        float4 v = make_float4(sm * r[i][0], sm * r[i][1], sm * r[i][2], sm * r[i][3]);
        if (S) {
            v.x = fmaf(sa, S[e], v.x);     v.y = fmaf(sa, S[e + 1], v.y);
            v.z = fmaf(sa, S[e + 2], v.z); v.w = fmaf(sa, S[e + 3], v.w);
        }
        *(float4*)&C[e] = v;
    }
    __syncthreads();
}

__device__ __forceinline__ void mm64gt(float* __restrict__ C, const float* __restrict__ Ag,
    const float* __restrict__ Bm, int tid)
{
    const int ty = tid >> 4, tx = tid & 15;
    float r[4][4] = {};
    __syncthreads();
    #pragma unroll 4
    for (int k = 0; k < 64; ++k) {
        float4 b4 = *(const float4*)&Bm[(k << 6) + (tx << 2)];
        #pragma unroll
        for (int i = 0; i < 4; ++i) {
            float a = Ag[(((ty << 2) + i) << 6) + k];
            r[i][0] = fmaf(a, b4.x, r[i][0]);
            r[i][1] = fmaf(a, b4.y, r[i][1]);
            r[i][2] = fmaf(a, b4.z, r[i][2]);
            r[i][3] = fmaf(a, b4.w, r[i][3]);
        }
    }
    __syncthreads();
    #pragma unroll
    for (int i = 0; i < 4; ++i) {
        int e = (((ty << 2) + i) << 6) + (tx << 2);
        *(float4*)&C[e] = make_float4(r[i][0], r[i][1], r[i][2], r[i][3]);
    }
    __syncthreads();
}

__global__ __launch_bounds__(256) void k_pinv(const float* __restrict__ attn2,
    const float* __restrict__ mx, const float* __restrict__ t3g, float* __restrict__ t2g)
{
    __shared__ float Zs[4096], Ab[4096], Db[4096];
    const int tid = threadIdx.x;
    const int bh = blockIdx.x;
    const float inv = 1.0f / (mx[0] * mx[1]);
    const float* a2 = attn2 + (size_t)bh * 4096;
    for (int e = tid; e < 4096; e += 256) {
        int i = e >> 6, j = e & 63;
        Zs[e] = a2[(j << 6) + i] * inv;
    }
    for (int it = 0; it < 6; ++it) {
        mm64gt(Ab, a2, Zs, tid);
        mm64t(Db, Ab, Ab, Ab, 7.f, -1.f, tid);
        for (int e = tid; e < 4096; e += 256) {
            int i = e >> 6, j = e & 63;
            Db[e] = ((i == j) ? 15.f : 0.f) - Db[e];
        }
        mm64t(Ab, Zs, Ab, nullptr, 0.f, 1.f, tid);
        mm64t(Zs, Ab, Db, Zs, 3.25f, -0.25f, tid);
    }
    for (int e = tid; e < 4096; e += 256) Ab[e] = t3g[(size_t)bh * 4096 + e];
    mm64t(Db, Zs, Ab, nullptr, 0.f, 1.f, tid);
    for (int e = tid; e < 4096; e += 256) t2g[(size_t)bh * 4096 + e] = Db[e];
}

// ---------------- K7: out1 = softmax(mq@k_l^T) @ t2  (MFMA, conv in k_conv) --------
__global__ __launch_bounds__(256) void k_attn1(const float* __restrict__ mq,
    const float* __restrict__ klg, const float* __restrict__ t2g,
    float* __restrict__ opre)
{
    __shared__ __align__(16) _Float16 klh[4096], kll[4096];
    __shared__ __align__(16) _Float16 t2h[4096], t2l[4096];
    __shared__ __align__(16) unsigned int qps[64 * 68];
    const int bh = blockIdx.x;
    const int b = bh >> 3, h = bh & 7;
    const int rgb = blockIdx.y;
    const int tid = threadIdx.x;
    const int wv = tid >> 6, lane = tid & 63;
    const int lg = lane >> 4, ll = lane & 15;

    _Float16* qh_ = (_Float16*)qps;
    _Float16* ql_ = qh_ + 4096;

    #pragma unroll
    for (int it = 0; it < 4; ++it) {
        int e = tid + 256 * it;
        int r = e >> 4, c0 = (e & 15) << 2;
        float4 kx = *(const float4*)(klg + (size_t)bh * 4096 + r * 64 + c0);
        f16x4 hh, lo;
        float vals[4] = {kx.x, kx.y, kx.z, kx.w};
        #pragma unroll
        for (int i = 0; i < 4; ++i) {
            _Float16 hv = (_Float16)vals[i];
            hh[i] = hv; lo[i] = (_Float16)(vals[i] - (float)hv);
        }
        int off = r * 64 + (((c0 >> 3) ^ (r & 7)) << 3) + (c0 & 7);
        *(f16x4*)&klh[off] = hh;
        *(f16x4*)&kll[off] = lo;
    }
    {
        const int r0 = (tid & 31) * 2, cb = (tid >> 5) * 4;
        #pragma unroll
        for (int ci = 0; ci < 2; ++ci) {
            int c0 = cb + 32 * ci;
            float4 v0 = *(const float4*)(t2g + (size_t)bh * 4096 + (size_t)r0 * 64 + c0);
            float4 v1 = *(const float4*)(t2g + (size_t)bh * 4096 + (size_t)(r0 + 1) * 64 + c0);
            float a0[4] = {v0.x, v0.y, v0.z, v0.w};
            float a1[4] = {v1.x, v1.y, v1.z, v1.w};
            #pragma unroll
            for (int i = 0; i < 4; ++i) {
                int c = c0 + i;
                _Float16 h0 = (_Float16)a0[i], h1 = (_Float16)a1[i];
                _Float16 e0 = (_Float16)(a0[i] - (float)h0), e1 = (_Float16)(a1[i] - (float)h1);
                int off = c * 64 + (((r0 >> 3) ^ (c & 7)) << 3) + (r0 & 7);
                *(unsigned int*)&t2h[off] = (unsigned int)hbits(h0) | ((unsigned int)hbits(h1) << 16);
                *(unsigned int*)&t2l[off] = (unsigned int)hbits(e0) | ((unsigned int)hbits(e1) << 16);
            }
        }
    }

    const float* mqb = mq + (size_t)bh * NP * DH;
    f16x8 bkh[2], bkl2[2], bth[2], btl2[2];

    for (int t = 0; t < 8; ++t) {
        const int row0 = (rgb << 9) + (t << 6);
        #pragma unroll
        for (int it = 0; it < 4; ++it) {
            int e = tid + 256 * it;
            int r = e >> 4, c0 = (e & 15) << 2;
            float4 qv = *(const float4*)(mqb + (size_t)(row0 + r) * DH + c0);
            f16x4 hh, lo;
            float vals[4] = {qv.x, qv.y, qv.z, qv.w};
            #pragma unroll
            for (int i = 0; i < 4; ++i) {
                _Float16 hv = (_Float16)vals[i];
                hh[i] = hv; lo[i] = (_Float16)(vals[i] - (float)hv);
            }
            int off = r * 64 + (((c0 >> 3) ^ (r & 7)) << 3) + (c0 & 7);
            *(f16x4*)&qh_[off] = hh;
            *(f16x4*)&ql_[off] = lo;
        }
        __syncthreads();
        if (t == 0) {
            #pragma unroll
            for (int ks = 0; ks < 2; ++ks) {
                int k0 = 32 * ks + (lg << 3);
                int br = 16 * wv + ll;
                int boff = br * 64 + (((k0 >> 3) ^ (br & 7)) << 3);
                bkh[ks]  = *(const f16x8*)&klh[boff];
                bkl2[ks] = *(const f16x8*)&kll[boff];
                bth[ks]  = *(const f16x8*)&t2h[boff];
                btl2[ks] = *(const f16x8*)&t2l[boff];
            }
        }
        f16x8 ah[2][4], al[2][4];
        #pragma unroll
        for (int ks = 0; ks < 2; ++ks) {
            int k0 = 32 * ks + (lg << 3);
            #pragma unroll
            for (int m = 0; m < 4; ++m) {
                int arw = 16 * m + ll;
                int aoff = arw * 64 + (((k0 >> 3) ^ (arw & 7)) << 3);
                ah[ks][m] = *(const f16x8*)&qh_[aoff];
                al[ks][m] = *(const f16x8*)&ql_[aoff];
            }
        }
        __syncthreads();
        f32x4 accs[4] = {};
        #pragma unroll
        for (int ks = 0; ks < 2; ++ks)
            #pragma unroll
            for (int m = 0; m < 4; ++m) {
                accs[m] = __builtin_amdgcn_mfma_f32_16x16x32_f16(ah[ks][m], bkh[ks], accs[m], 0, 0, 0);
                accs[m] = __builtin_amdgcn_mfma_f32_16x16x32_f16(ah[ks][m], bkl2[ks], accs[m], 0, 0, 0);
                accs[m] = __builtin_amdgcn_mfma_f32_16x16x32_f16(al[ks][m], bkh[ks], accs[m], 0, 0, 0);
            }
        #pragma unroll
        for (int m = 0; m < 4; ++m)
            #pragma unroll
            for (int rgi = 0; rgi < 4; ++rgi)
                qps[(16 * m + lg * 4 + rgi) * 68 + 16 * wv + ll] = __float_as_uint(accs[m][rgi]);
        __syncthreads();
        {
            const int r = tid >> 2, q4 = tid & 3;
            float s[16];
            #pragma unroll
            for (int j = 0; j < 16; ++j) s[j] = __uint_as_float(qps[r * 68 + q4 * 16 + j]);
            float rmax = s[0];
            #pragma unroll
            for (int j = 1; j < 16; ++j) rmax = fmaxf(rmax, s[j]);
            rmax = fmaxf(rmax, __shfl_xor(rmax, 1));
            rmax = fmaxf(rmax, __shfl_xor(rmax, 2));
            float p[16], rsum = 0.f;
            #pragma unroll
            for (int j = 0; j < 16; ++j) { p[j] = expf(s[j] - rmax); rsum += p[j]; }
            rsum += __shfl_xor(rsum, 1);
            rsum += __shfl_xor(rsum, 2);
            float rinv = 1.f / rsum;
            #pragma unroll
            for (int j = 0; j < 16; ++j) p[j] *= rinv;
            #pragma unroll
            for (int i2 = 0; i2 < 8; ++i2) {
                float p0 = p[2 * i2], p1 = p[2 * i2 + 1];
                _Float16 h0 = (_Float16)p0, h1 = (_Float16)p1;
                _Float16 e0 = (_Float16)(p0 - (float)h0), e1 = (_Float16)(p1 - (float)h1);
                qps[r * 68 + q4 * 8 + i2]      = (unsigned int)hbits(h0) | ((unsigned int)hbits(h1) << 16);
                qps[r * 68 + 32 + q4 * 8 + i2] = (unsigned int)hbits(e0) | ((unsigned int)hbits(e1) << 16);
            }
        }
        __syncthreads();
        f32x4 acco[4] = {};
        #pragma unroll
        for (int ks = 0; ks < 2; ++ks)
            #pragma unroll
            for (int m = 0; m < 4; ++m) {
                int prow = 16 * m + ll;
                union { uint4 u; f16x8 f; } ph, pe;
                ph.u = *(const uint4*)&qps[prow * 68 + 16 * ks + lg * 4];
                pe.u = *(const uint4*)&qps[prow * 68 + 32 + 16 * ks + lg * 4];
                acco[m] = __builtin_amdgcn_mfma_f32_16x16x32_f16(ph.f, bth[ks], acco[m], 0, 0, 0);
                acco[m] = __builtin_amdgcn_mfma_f32_16x16x32_f16(ph.f, btl2[ks], acco[m], 0, 0, 0);
                acco[m] = __builtin_amdgcn_mfma_f32_16x16x32_f16(pe.f, bth[ks], acco[m], 0, 0, 0);
            }
        {
            int col = 16 * wv + ll;
            #pragma unroll
            for (int m = 0; m < 4; ++m) {
                int rb = row0 + 16 * m + lg * 4;
                #pragma unroll
                for (int rgi = 0; rgi < 4; ++rgi)
                    opre[((size_t)b * NP + rb + rgi) * DIM + h * DH + col] = acco[m][rgi];
            }
        }
        __syncthreads();
    }
}

// ---------------- K7b: opre += depthwise conv(v)  (LDS-staged sliding window) ------------
__global__ __launch_bounds__(256) void k_conv(const float* __restrict__ vb,
    const float* __restrict__ cwg, float* __restrict__ opre)
{
    __shared__ float vs[96][68];
    __shared__ float cw[33];
    const int bh = blockIdx.x;
    const int b = bh >> 3, h = bh & 7;
    const int row0 = blockIdx.y << 6;
    const int tid = threadIdx.x;
    const float* vbase = vb + (size_t)bh * NTOT * DH;
    #pragma unroll
    for (int it = 0; it < 6; ++it) {
        int e = tid + 256 * it;
        int r = e >> 4, c4 = (e & 15) << 2;
        int gr = row0 - 16 + r;
        float4 v = (gr >= 0) ? *(const float4*)(vbase + (size_t)gr * DH + c4)
                             : make_float4(0.f, 0.f, 0.f, 0.f);
        *(float4*)&vs[r][c4] = v;
    }
    if (tid < 33) cw[tid] = cwg[h * 33 + tid];
    __syncthreads();
    const int ty = tid >> 4, c4 = (tid & 15) << 2;
    #pragma unroll
    for (int i = 0; i < 4; ++i) {
        int lr = ty * 4 + i;
        float4 a = make_float4(0.f, 0.f, 0.f, 0.f);
        #pragma unroll 33
        for (int k = 0; k < 33; ++k) {
            float w = cw[k];
            const float* p = &vs[lr + k][c4];
            a.x = fmaf(w, p[0], a.x); a.y = fmaf(w, p[1], a.y);
            a.z = fmaf(w, p[2], a.z); a.w = fmaf(w, p[3], a.w);
        }
        float* op = opre + ((size_t)b * NP + row0 + lr) * DIM + h * DH + c4;
        float4 o = *(const float4*)op;
        o.x += a.x; o.y += a.y; o.z += a.z; o.w += a.w;
        *(float4*)op = o;
    }
}

extern "C" void kernel_launch(void* const* d_in, const int* in_sizes, int n_in,
                              void* d_out, int out_size, void* d_ws, size_t ws_size,
                              hipStream_t stream)
{
    const float* x   = (const float*)d_in[0];
    const float* ps  = (const float*)d_in[1];
    const float* wq  = (const float*)d_in[2];
    const float* wo  = (const float*)d_in[3];
    const float* cwg = (const float*)d_in[4];
    float* out = (float*)d_out;
    float* ws  = (float*)d_ws;

    float* mq   = out;               // d_out doubles as mq scratch; k_gemm<1> overwrites last
    float* kb   = ws + OFF_K;
    float* vb   = ws + OFF_V;
    float* ql   = ws + OFF_QL;
    float* kl   = ws + OFF_KL;
    float* a2   = ws + OFF_A2;
    float* t3   = ws + OFF_T3;
    float* t2   = ws + OFF_T2;
    float* mx   = ws + OFF_MAX;
    float* opre = ws + OFF_OPRE;
    float* pacc = opre;
    float* pm   = opre + 3145728ull;
    float* pl   = pm + 49152ull;
    _Float16* BTqh = (_Float16*)(ws + OFF_QL);
    _Float16* BTql = BTqh + 1536 * 512;
    _Float16* BToh = (_Float16*)(ws + OFF_K);
    _Float16* BTol = BToh + 512 * 512;

    k_cvtw        <<<dim3(24, 8), 256, 0, stream>>>(wq, BTqh, BTql, 512, 1536);
    k_gemm_split<0><<<4608, 256, 0, stream>>>(x, ps, BTqh, BTql, mq, kb, vb);
    k_land        <<<4096, 256, 0, stream>>>(mq, kb, ql, kl);
    k_sim2        <<<32, 256, 0, stream>>>(ql, kl, a2, mx);
    k_maxes       <<<32, 64, 0, stream>>>(a2, mx);
    k_sim3part    <<<dim3(32, NCH), 256, 0, stream>>>(ql, kb, vb, pacc, pm, pl);
    k_sim3comb    <<<32, 256, 0, stream>>>(pacc, pm, pl, t3);
    k_cvtw        <<<dim3(8, 8), 256, 0, stream>>>(wo, BToh, BTol, 512, 512);
    k_pinv        <<<32, 256, 0, stream>>>(a2, mx, t3, t2);
    k_attn1       <<<dim3(32, 8), 256, 0, stream>>>(mq, kl, t2, opre);
    k_conv        <<<dim3(32, 64), 256, 0, stream>>>(vb, cwg, opre);
    k_gemm_split<1><<<512, 256, 0, stream>>>(opre, nullptr, BToh, BTol, out, nullptr, nullptr);
}

// Round 13
// 573.267 us; speedup vs baseline: 1.3002x; 1.0173x over previous
//
#include <hip/hip_runtime.h>
#include <math.h>

#define Bb 4
#define Hh 8
#define NP 4096
#define PTOT 8192
#define NTOT 12288
#define DIM 512
#define DH 64
#define SCALE 0.125f
#define NCH 24
#define CHUNK 512

typedef __attribute__((ext_vector_type(8))) _Float16 f16x8;
typedef __attribute__((ext_vector_type(4))) _Float16 f16x4;
typedef __attribute__((ext_vector_type(4))) float f32x4;

// ---------------- workspace layout (float offsets) ----------------
#define SZ_K    (4ull*8*12288*64)      // 25,165,824
#define SZ_L    (32ull*64*64)          // 131,072
#define OFF_K    0ull
#define OFF_V    (OFF_K + SZ_K)
#define OFF_QL   (OFF_V + SZ_K)        // (BTq aliases from here during gemm<0>)
#define OFF_KL   (OFF_QL + SZ_L)       // kl final (written by k_landc, after BTq dead)
#define OFF_A2   (OFF_KL + SZ_L)
#define OFF_T3   (OFF_A2 + SZ_L)
#define OFF_T2   (OFF_T3 + SZ_L)
#define OFF_MAX  (OFF_T2 + SZ_L)
#define OFF_OPRE (OFF_MAX + 16ull)
#define SZ_OPRE  (4ull*4096*512)       // 8,388,608
#define OFF_QLA  (OFF_OPRE + SZ_OPRE)  // q-landmarks (direct from gemm<0> epilogue)
#define OFF_KLP  (OFF_QLA + SZ_L)      // k-landmark 64-row partials [32][192][64]
// total end = 59,899,920 floats ≈ 239.6 MB (< 256 MiB d_ws)

__device__ __forceinline__ unsigned short hbits(_Float16 x) {
    union { _Float16 f; unsigned short u; } c; c.f = x; return c.u;
}

// ---------------- transpose + fp16-split weights: w[K][N] -> BT[N][K] hi/lo ----------------
__global__ __launch_bounds__(256) void k_cvtw(const float* __restrict__ w,
    _Float16* __restrict__ bh, _Float16* __restrict__ bl, int K, int N)
{
    __shared__ float t[64][65];
    const int n0 = blockIdx.x * 64, k0 = blockIdx.y * 64;
    const int tid = threadIdx.x;
    #pragma unroll
    for (int i = 0; i < 4; ++i) {
        int r = (tid >> 4) + i * 16;
        int c = (tid & 15) * 4;
        float4 v = *(const float4*)(w + (size_t)(k0 + r) * N + n0 + c);
        t[r][c] = v.x; t[r][c+1] = v.y; t[r][c+2] = v.z; t[r][c+3] = v.w;
    }
    __syncthreads();
    const int n = tid >> 2, kq = (tid & 3) * 16;
    f16x8 h8[2], l8[2];
    #pragma unroll
    for (int j = 0; j < 16; ++j) {
        float a = t[kq + j][n];
        _Float16 hh = (_Float16)a;
        _Float16 ll = (_Float16)(a - (float)hh);
        h8[j >> 3][j & 7] = hh;
        l8[j >> 3][j & 7] = ll;
    }
    size_t o = (size_t)(n0 + n) * K + k0 + kq;
    *(f16x8*)(bh + o) = h8[0]; *(f16x8*)(bh + o + 8) = h8[1];
    *(f16x8*)(bl + o) = l8[0]; *(f16x8*)(bl + o + 8) = l8[1];
}

// ---------------- fp16-split MFMA GEMM, 2-phase dbuf, depth-2 prefetch, XCD swizzle ------
// MODE 0 additionally emits landmark partial sums (q direct, k 64-row halves).
__device__ __forceinline__ int hoff(int r, int slot) {
    return r * 32 + (((slot ^ (r >> 1)) & 3) << 3);
}

template<int MODE>
__global__ __launch_bounds__(256) void k_gemm_split(
    const float* __restrict__ Asrc0, const float* __restrict__ Asrc1,
    const _Float16* __restrict__ BTh, const _Float16* __restrict__ BTl,
    float* __restrict__ out0, float* __restrict__ out1, float* __restrict__ out2,
    float* __restrict__ qla, float* __restrict__ klp)
{
    __shared__ __align__(16) _Float16 Ah[2][128 * 32], Al[2][128 * 32];
    __shared__ __align__(16) _Float16 Bh[2][128 * 32], Bl[2][128 * 32];
    const int NB = (MODE == 0) ? 12 : 4;
    const int id = blockIdx.x;
    const int w8 = id % (NB * 8);
    const int n0 = (w8 >> 3) * 128;
    const int m0 = ((id / (NB * 8)) * 8 + (w8 & 7)) * 128;
    const int tid = threadIdx.x;
    const int wv = tid >> 6, lane = tid & 63;
    const int wr = wv >> 1, wc = wv & 1;
    const int kslot = lane >> 4;

    int ar[2], asl[2];
    const float* aptr[2];
    #pragma unroll
    for (int i = 0; i < 2; ++i) {
        int id2 = tid + 256 * i;
        ar[i] = id2 >> 2; asl[i] = id2 & 3;
        int grow = m0 + ar[i];
        if (MODE == 0) {
            int bi = grow / NTOT;
            int pos = grow - bi * NTOT;
            aptr[i] = (pos < NP) ? (Asrc0 + ((size_t)bi * NP + pos) * DIM)
                                 : (Asrc1 + ((size_t)bi * PTOT + (pos - NP)) * DIM);
        } else {
            aptr[i] = Asrc0 + (size_t)grow * DIM;
        }
    }

    float4 a0[2], a1[2];
    f16x8 vbh[2], vbl[2];

    auto LOADT = [&](int k0) {
        #pragma unroll
        for (int i = 0; i < 2; ++i) {
            a0[i] = *(const float4*)(aptr[i] + k0 + asl[i] * 8);
            a1[i] = *(const float4*)(aptr[i] + k0 + asl[i] * 8 + 4);
            size_t bo = (size_t)(n0 + ar[i]) * DIM + k0 + asl[i] * 8;
            vbh[i] = *(const f16x8*)(BTh + bo);
            vbl[i] = *(const f16x8*)(BTl + bo);
        }
    };
    auto WRITET = [&](int buf) {
        #pragma unroll
        for (int i = 0; i < 2; ++i) {
            f16x8 h, l;
            float vals[8] = {a0[i].x, a0[i].y, a0[i].z, a0[i].w,
                             a1[i].x, a1[i].y, a1[i].z, a1[i].w};
            #pragma unroll
            for (int j = 0; j < 8; ++j) {
                _Float16 hh = (_Float16)vals[j];
                h[j] = hh;
                l[j] = (_Float16)(vals[j] - (float)hh);
            }
            int o = hoff(ar[i], asl[i]);
            *(f16x8*)&Ah[buf][o] = h;
            *(f16x8*)&Al[buf][o] = l;
            *(f16x8*)&Bh[buf][o] = vbh[i];
            *(f16x8*)&Bl[buf][o] = vbl[i];
        }
    };

    LOADT(0);
    WRITET(0);
    LOADT(32);
    int cur = 0;

    f32x4 acc[4][4] = {};
    for (int t = 0; t < 16; ++t) {
        __syncthreads();
        f16x8 afh[4], afl[4];
        #pragma unroll
        for (int m = 0; m < 4; ++m) {
            int o = hoff(wr * 64 + m * 16 + (lane & 15), kslot);
            afh[m] = *(const f16x8*)&Ah[cur][o];
            afl[m] = *(const f16x8*)&Al[cur][o];
        }
        f16x8 bfh[4], bfl[4];
        #pragma unroll
        for (int n = 0; n < 4; ++n) {
            int o = hoff(wc * 64 + n * 16 + (lane & 15), kslot);
            bfh[n] = *(const f16x8*)&Bh[cur][o];
            bfl[n] = *(const f16x8*)&Bl[cur][o];
        }
        if (t < 15) WRITET(cur ^ 1);
        if (t < 14) LOADT((t + 2) * 32);
        #pragma unroll
        for (int n = 0; n < 4; ++n)
            #pragma unroll
            for (int m = 0; m < 4; ++m) {
                acc[m][n] = __builtin_amdgcn_mfma_f32_16x16x32_f16(afh[m], bfh[n], acc[m][n], 0, 0, 0);
                acc[m][n] = __builtin_amdgcn_mfma_f32_16x16x32_f16(afh[m], bfl[n], acc[m][n], 0, 0, 0);
                acc[m][n] = __builtin_amdgcn_mfma_f32_16x16x32_f16(afl[m], bfh[n], acc[m][n], 0, 0, 0);
            }
        cur ^= 1;
    }
    #pragma unroll
    for (int m = 0; m < 4; ++m) {
        #pragma unroll
        for (int n = 0; n < 4; ++n) {
            int gcol = n0 + wc * 64 + n * 16 + (lane & 15);
            int rbase = m0 + wr * 64 + m * 16 + (lane >> 4) * 4;
            if (MODE == 1) {
                #pragma unroll
                for (int r = 0; r < 4; ++r)
                    out0[(size_t)(rbase + r) * DIM + gcol] = acc[m][n][r];
            } else {
                int which = gcol >> 9, h = (gcol >> 6) & 7, d = gcol & 63;
                #pragma unroll
                for (int r = 0; r < 4; ++r) {
                    int row = rbase + r;
                    int bi = row / NTOT;
                    int p = row - bi * NTOT;
                    float v = acc[m][n][r];
                    if (which == 0) {
                        if (p < NP) out0[(((size_t)bi * Hh + h) * NP + p) * DH + d] = v * SCALE;
                    } else if (which == 1) {
                        out1[(((size_t)bi * Hh + h) * NTOT + p) * DH + d] = v;
                    } else {
                        out2[(((size_t)bi * Hh + h) * NTOT + p) * DH + d] = v;
                    }
                }
            }
        }
    }
    // ---- fused landmark partials (MODE 0 only) ----
    if (MODE == 0) {
        const int bi_t = m0 / NTOT;
        const int pos0 = m0 - bi_t * NTOT;
        const int basec = n0 + wc * 64;
        const int whichc = basec >> 9;
        const int hc = (basec >> 6) & 7;
        if ((whichc == 0 && pos0 < NP) || whichc == 1) {
            #pragma unroll
            for (int n = 0; n < 4; ++n) {
                float s = 0.f;
                #pragma unroll
                for (int m = 0; m < 4; ++m)
                    #pragma unroll
                    for (int r = 0; r < 4; ++r) s += acc[m][n][r];
                s += __shfl_xor(s, 16);
                s += __shfl_xor(s, 32);
                if ((lane >> 4) == 0) {
                    int d = n * 16 + (lane & 15);
                    int grp = (pos0 >> 6) + wr;          // 64-row group index
                    if (whichc == 0) {
                        qla[(((size_t)bi_t * Hh + hc) * 64 + grp) * 64 + d] = s * (SCALE / 64.f);
                    } else {
                        klp[(((size_t)bi_t * Hh + hc) * 192 + grp) * 64 + d] = s;
                    }
                }
            }
        }
    }
}

// ---------------- K2': combine k-landmark partials (3 halves -> one 192-row mean) --------
__global__ __launch_bounds__(256) void k_landc(const float* __restrict__ klp,
    float* __restrict__ kl)
{
    const int bh = blockIdx.x;
    const int tid = threadIdx.x;
    for (int e = tid; e < 4096; e += 256) {
        int i = e >> 6, d = e & 63;
        size_t base = ((size_t)bh * 192 + 3 * i) * 64 + d;
        kl[(size_t)bh * 4096 + e] = (klp[base] + klp[base + 64] + klp[base + 128]) * (1.f / 192.f);
    }
}

// ---------------- K3: attn2 = softmax(q_l @ k_l^T); also zero-inits mx ----------------
__global__ __launch_bounds__(256) void k_sim2(const float* __restrict__ ql,
    const float* __restrict__ kl, float* __restrict__ a2, float* __restrict__ mx)
{
    __shared__ float qs[64][64];
    __shared__ float ks[64][65];
    __shared__ float S[64][65];
    const int tid = threadIdx.x;
    const int bh = blockIdx.x;
    if (bh == 0 && tid < 2) mx[tid] = 0.f;
    for (int e = tid; e < 4096; e += 256) {
        qs[e >> 6][e & 63] = ql[(size_t)bh * 4096 + e];
        ks[e >> 6][e & 63] = kl[(size_t)bh * 4096 + e];
    }
    __syncthreads();
    for (int sI = 0; sI < 16; ++sI) {
        int e = (sI << 8) + tid;
        int i = e >> 6, j = e & 63;
        float acc = 0.f;
        #pragma unroll 16
        for (int d = 0; d < 64; ++d) acc = fmaf(qs[i][d], ks[j][d], acc);
        S[i][j] = acc;
    }
    __syncthreads();
    const int wv = tid >> 6, lane = tid & 63;
    for (int i = wv; i < 64; i += 4) {
        float v = S[i][lane];
        float mxv = v;
        #pragma unroll
        for (int off = 32; off; off >>= 1) mxv = fmaxf(mxv, __shfl_xor(mxv, off));
        float p = expf(v - mxv);
        float sm = p;
        #pragma unroll
        for (int off = 32; off; off >>= 1) sm += __shfl_xor(sm, off);
        a2[((size_t)bh * 64 + i) * 64 + lane] = p / sm;
    }
}

// ---------------- K4: global max of row/col abs-sums of attn2 ----------------
__global__ __launch_bounds__(64) void k_maxes(const float* __restrict__ a2,
    float* __restrict__ mx)
{
    const int bh = blockIdx.x;
    const int i = threadIdx.x;
    const float* base = a2 + (size_t)bh * 4096;
    float cs = 0.f, rs = 0.f;
    for (int j = 0; j < 64; ++j) {
        cs += fabsf(base[i * 64 + j]);
        rs += fabsf(base[j * 64 + i]);
    }
    #pragma unroll
    for (int off = 32; off; off >>= 1) {
        cs = fmaxf(cs, __shfl_xor(cs, off));
        rs = fmaxf(rs, __shfl_xor(rs, off));
    }
    if (i == 0) {
        atomicMax((unsigned int*)&mx[0], __float_as_uint(cs));
        atomicMax((unsigned int*)&mx[1], __float_as_uint(rs));
    }
}

// ---------------- K5a: sim3 partials — fp16-split MFMA flash over a 512-row chunk ----------
__global__ __launch_bounds__(256) void k_sim3part(const float* __restrict__ qlg,
    const float* __restrict__ kb, const float* __restrict__ vb,
    float* __restrict__ pacc, float* __restrict__ pm, float* __restrict__ pl)
{
    __shared__ __align__(16) _Float16 qsh[4096], qsl[4096];
    __shared__ __align__(16) _Float16 kvh[4096], kvl[4096];
    __shared__ __align__(16) unsigned int pss[64][68];
    __shared__ float corr_s[64];
    const int bh = blockIdx.x, ch = blockIdx.y;
    const int tid = threadIdx.x;
    const int wv = tid >> 6, lane = tid & 63;
    const int lg = lane >> 4, ll = lane & 15;

    #pragma unroll
    for (int it = 0; it < 4; ++it) {
        int e = tid + 256 * it;
        int r = e >> 4, c0 = (e & 15) << 2;
        float4 qv = *(const float4*)(qlg + (size_t)bh * 4096 + r * 64 + c0);
        f16x4 h, l;
        float vals[4] = {qv.x, qv.y, qv.z, qv.w};
        #pragma unroll
        for (int i = 0; i < 4; ++i) {
            _Float16 hh = (_Float16)vals[i];
            h[i] = hh; l[i] = (_Float16)(vals[i] - (float)hh);
        }
        int off = r * 64 + (((c0 >> 3) ^ (r & 7)) << 3) + (c0 & 7);
        *(f16x4*)&qsh[off] = h;
        *(f16x4*)&qsl[off] = l;
    }

    const float* kc = kb + ((size_t)bh * NTOT + ch * CHUNK) * DH;
    const float* vc = vb + ((size_t)bh * NTOT + ch * CHUNK) * DH;

    float m_run = -INFINITY, l_run = 0.f;
    f32x4 acc_o[4] = {};

    for (int t = 0; t < CHUNK / 64; ++t) {
        __syncthreads();
        #pragma unroll
        for (int it = 0; it < 4; ++it) {
            int e = tid + 256 * it;
            int r = e >> 4, c0 = (e & 15) << 2;
            float4 kx = *(const float4*)(kc + (size_t)(t * 64 + r) * DH + c0);
            f16x4 h, l;
            float vals[4] = {kx.x, kx.y, kx.z, kx.w};
            #pragma unroll
            for (int i = 0; i < 4; ++i) {
                _Float16 hh = (_Float16)vals[i];
                h[i] = hh; l[i] = (_Float16)(vals[i] - (float)hh);
            }
            int off = r * 64 + (((c0 >> 3) ^ (r & 7)) << 3) + (c0 & 7);
            *(f16x4*)&kvh[off] = h;
            *(f16x4*)&kvl[off] = l;
        }
        __syncthreads();
        f32x4 accs[4] = {};
        #pragma unroll
        for (int ks = 0; ks < 2; ++ks) {
            int k0 = 32 * ks + (lg << 3);
            int brow = 16 * wv + ll;
            int boff = brow * 64 + (((k0 >> 3) ^ (brow & 7)) << 3);
            f16x8 bh8 = *(const f16x8*)&kvh[boff];
            f16x8 bl8 = *(const f16x8*)&kvl[boff];
            #pragma unroll
            for (int m = 0; m < 4; ++m) {
                int arow = 16 * m + ll;
                int aoff = arow * 64 + (((k0 >> 3) ^ (arow & 7)) << 3);
                f16x8 ah8 = *(const f16x8*)&qsh[aoff];
                f16x8 al8 = *(const f16x8*)&qsl[aoff];
                accs[m] = __builtin_amdgcn_mfma_f32_16x16x32_f16(ah8, bh8, accs[m], 0, 0, 0);
                accs[m] = __builtin_amdgcn_mfma_f32_16x16x32_f16(ah8, bl8, accs[m], 0, 0, 0);
                accs[m] = __builtin_amdgcn_mfma_f32_16x16x32_f16(al8, bh8, accs[m], 0, 0, 0);
            }
        }
        #pragma unroll
        for (int m = 0; m < 4; ++m)
            #pragma unroll
            for (int rg = 0; rg < 4; ++rg)
                pss[16 * m + lg * 4 + rg][16 * wv + ll] = __float_as_uint(accs[m][rg]);
        __syncthreads();
        {
            const int r = tid >> 2, q = tid & 3;
            float s[16];
            uint4 u0 = *(const uint4*)&pss[r][q * 16];
            uint4 u1 = *(const uint4*)&pss[r][q * 16 + 4];
            uint4 u2 = *(const uint4*)&pss[r][q * 16 + 8];
            uint4 u3 = *(const uint4*)&pss[r][q * 16 + 12];
            s[0]=__uint_as_float(u0.x); s[1]=__uint_as_float(u0.y); s[2]=__uint_as_float(u0.z); s[3]=__uint_as_float(u0.w);
            s[4]=__uint_as_float(u1.x); s[5]=__uint_as_float(u1.y); s[6]=__uint_as_float(u1.z); s[7]=__uint_as_float(u1.w);
            s[8]=__uint_as_float(u2.x); s[9]=__uint_as_float(u2.y); s[10]=__uint_as_float(u2.z); s[11]=__uint_as_float(u2.w);
            s[12]=__uint_as_float(u3.x); s[13]=__uint_as_float(u3.y); s[14]=__uint_as_float(u3.z); s[15]=__uint_as_float(u3.w);
            float lmax = s[0];
            #pragma unroll
            for (int i = 1; i < 16; ++i) lmax = fmaxf(lmax, s[i]);
            lmax = fmaxf(lmax, __shfl_xor(lmax, 1));
            lmax = fmaxf(lmax, __shfl_xor(lmax, 2));
            float mnew = fmaxf(m_run, lmax);
            float corr = expf(m_run - mnew);
            float p[16], rsum = 0.f;
            #pragma unroll
            for (int i = 0; i < 16; ++i) { p[i] = expf(s[i] - mnew); rsum += p[i]; }
            rsum += __shfl_xor(rsum, 1);
            rsum += __shfl_xor(rsum, 2);
            l_run = l_run * corr + rsum;
            m_run = mnew;
            if (q == 0) corr_s[r] = corr;
            #pragma unroll
            for (int i2 = 0; i2 < 8; ++i2) {
                float p0 = p[2 * i2], p1 = p[2 * i2 + 1];
                _Float16 h0 = (_Float16)p0, h1 = (_Float16)p1;
                _Float16 e0 = (_Float16)(p0 - (float)h0), e1 = (_Float16)(p1 - (float)h1);
                pss[r][q * 8 + i2]      = (unsigned int)hbits(h0) | ((unsigned int)hbits(h1) << 16);
                pss[r][32 + q * 8 + i2] = (unsigned int)hbits(e0) | ((unsigned int)hbits(e1) << 16);
            }
        }
        {
            const int r0 = (tid & 31) * 2, cb = (tid >> 5) * 4;
            #pragma unroll
            for (int ci = 0; ci < 2; ++ci) {
                int c0 = cb + 32 * ci;
                float4 v0 = *(const float4*)(vc + (size_t)(t * 64 + r0) * DH + c0);
                float4 v1 = *(const float4*)(vc + (size_t)(t * 64 + r0 + 1) * DH + c0);
                float a0[4] = {v0.x, v0.y, v0.z, v0.w};
                float a1[4] = {v1.x, v1.y, v1.z, v1.w};
                #pragma unroll
                for (int i = 0; i < 4; ++i) {
                    int c = c0 + i;
                    _Float16 h0 = (_Float16)a0[i], h1 = (_Float16)a1[i];
                    _Float16 e0 = (_Float16)(a0[i] - (float)h0), e1 = (_Float16)(a1[i] - (float)h1);
                    int off = c * 64 + (((r0 >> 3) ^ (c & 7)) << 3) + (r0 & 7);
                    *(unsigned int*)&kvh[off] = (unsigned int)hbits(h0) | ((unsigned int)hbits(h1) << 16);
                    *(unsigned int*)&kvl[off] = (unsigned int)hbits(e0) | ((unsigned int)hbits(e1) << 16);
                }
            }
        }
        __syncthreads();
        #pragma unroll
        for (int m = 0; m < 4; ++m)
            #pragma unroll
            for (int rg = 0; rg < 4; ++rg)
                acc_o[m][rg] *= corr_s[16 * m + lg * 4 + rg];
        #pragma unroll
        for (int ks = 0; ks < 2; ++ks) {
            int k0 = 32 * ks + (lg << 3);
            int dh = 16 * wv + ll;
            int boff = dh * 64 + (((k0 >> 3) ^ (dh & 7)) << 3);
            f16x8 vh8 = *(const f16x8*)&kvh[boff];
            f16x8 vl8 = *(const f16x8*)&kvl[boff];
            #pragma unroll
            for (int m = 0; m < 4; ++m) {
                int prow = 16 * m + ll;
                union { uint4 u; f16x8 f; } ph, pe;
                ph.u = *(const uint4*)&pss[prow][16 * ks + lg * 4];
                pe.u = *(const uint4*)&pss[prow][32 + 16 * ks + lg * 4];
                acc_o[m] = __builtin_amdgcn_mfma_f32_16x16x32_f16(ph.f, vh8, acc_o[m], 0, 0, 0);
                acc_o[m] = __builtin_amdgcn_mfma_f32_16x16x32_f16(ph.f, vl8, acc_o[m], 0, 0, 0);
                acc_o[m] = __builtin_amdgcn_mfma_f32_16x16x32_f16(pe.f, vh8, acc_o[m], 0, 0, 0);
            }
        }
    }
    const size_t base = ((size_t)bh * NCH + ch) * 64;
    #pragma unroll
    for (int m = 0; m < 4; ++m)
        #pragma unroll
        for (int rg = 0; rg < 4; ++rg) {
            int row = 16 * m + lg * 4 + rg;
            pacc[(base + row) * 64 + 16 * wv + ll] = acc_o[m][rg];
        }
    if ((tid & 3) == 0) {
        int r = tid >> 2;
        pm[base + r] = m_run;
        pl[base + r] = l_run;
    }
}

// ---------------- K5b: combine sim3 partials -> t3 ----------------
__global__ __launch_bounds__(256) void k_sim3comb(const float* __restrict__ pacc,
    const float* __restrict__ pm, const float* __restrict__ pl, float* __restrict__ t3)
{
    __shared__ float w[NCH][64];
    __shared__ float Linv[64];
    const int bh = blockIdx.x;
    const int tid = threadIdx.x;
    if (tid < 64) {
        float M = -INFINITY;
        for (int c = 0; c < NCH; ++c)
            M = fmaxf(M, pm[((size_t)bh * NCH + c) * 64 + tid]);
        float L = 0.f;
        for (int c = 0; c < NCH; ++c) {
            float e = expf(pm[((size_t)bh * NCH + c) * 64 + tid] - M);
            w[c][tid] = e;
            L = fmaf(e, pl[((size_t)bh * NCH + c) * 64 + tid], L);
        }
        Linv[tid] = 1.f / L;
    }
    __syncthreads();
    const int wv = tid >> 6, lane = tid & 63;
    for (int p = 0; p < 16; ++p) {
        int i = (p << 2) + wv;
        float o = 0.f;
        for (int c = 0; c < NCH; ++c)
            o = fmaf(w[c][i], pacc[(((size_t)bh * NCH + c) * 64 + i) * 64 + lane], o);
        t3[((size_t)bh * 64 + i) * 64 + lane] = o * Linv[i];
    }
}

// ---------------- K6: pinv (LDS-resident, 256 thr, 4x4 register tiles) + t2 = z @ t3 -----
__device__ __forceinline__ void mm64t(float* __restrict__ C, const float* A,
    const float* Bm, const float* S, float sa, float sm, int tid)
{
    const int ty = tid >> 4, tx = tid & 15;
    float r[4][4] = {};
    __syncthreads();
    #pragma unroll 4
    for (int k = 0; k < 64; ++k) {
        float4 b4 = *(const float4*)&Bm[(k << 6) + (tx << 2)];
        #pragma unroll
        for (int i = 0; i < 4; ++i) {
            float a = A[(((ty << 2) + i) << 6) + k];
            r[i][0] = fmaf(a, b4.x, r[i][0]);
            r[i][1] = fmaf(a, b4.y, r[i][1]);
            r[i][2] = fmaf(a, b4.z, r[i][2]);
            r[i][3] = fmaf(a, b4.w, r[i][3]);
        }
    }
    __syncthreads();
    #pragma unroll
    for (int i = 0; i < 4; ++i) {
        int e = (((ty << 2) + i) << 6) + (tx << 2);
        float4 v = make_float4(sm * r[i][0], sm * r[i][1], sm * r[i][2], sm * r[i][3]);
        if (S) {
            v.x = fmaf(sa, S[e], v.x);     v.y = fmaf(sa, S[e + 1], v.y);
            v.z = fmaf(sa, S[e + 2], v.z); v.w = fmaf(sa, S[e + 3], v.w);
        }
        *(float4*)&C[e] = v;
    }
    __syncthreads();
}

__device__ __forceinline__ void mm64gt(float* __restrict__ C, const float* __restrict__ Ag,
    const float* __restrict__ Bm, int tid)
{
    const int ty = tid >> 4, tx = tid & 15;
    float r[4][4] = {};
    __syncthreads();
    #pragma unroll 4
    for (int k = 0; k < 64; ++k) {
        float4 b4 = *(const float4*)&Bm[(k << 6) + (tx << 2)];
        #pragma unroll
        for (int i = 0; i < 4; ++i) {
            float a = Ag[(((ty << 2) + i) << 6) + k];
            r[i][0] = fmaf(a, b4.x, r[i][0]);
            r[i][1] = fmaf(a, b4.y, r[i][1]);
            r[i][2] = fmaf(a, b4.z, r[i][2]);
            r[i][3] = fmaf(a, b4.w, r[i][3]);
        }
    }
    __syncthreads();
    #pragma unroll
    for (int i = 0; i < 4; ++i) {
        int e = (((ty << 2) + i) << 6) + (tx << 2);
        *(float4*)&C[e] = make_float4(r[i][0], r[i][1], r[i][2], r[i][3]);
    }
    __syncthreads();
}

__global__ __launch_bounds__(256) void k_pinv(const float* __restrict__ attn2,
    const float* __restrict__ mx, const float* __restrict__ t3g, float* __restrict__ t2g)
{
    __shared__ float Zs[4096], Ab[4096], Db[4096];
    const int tid = threadIdx.x;
    const int bh = blockIdx.x;
    const float inv = 1.0f / (mx[0] * mx[1]);
    const float* a2 = attn2 + (size_t)bh * 4096;
    for (int e = tid; e < 4096; e += 256) {
        int i = e >> 6, j = e & 63;
        Zs[e] = a2[(j << 6) + i] * inv;
    }
    for (int it = 0; it < 6; ++it) {
        mm64gt(Ab, a2, Zs, tid);
        mm64t(Db, Ab, Ab, Ab, 7.f, -1.f, tid);
        for (int e = tid; e < 4096; e += 256) {
            int i = e >> 6, j = e & 63;
            Db[e] = ((i == j) ? 15.f : 0.f) - Db[e];
        }
        mm64t(Ab, Zs, Ab, nullptr, 0.f, 1.f, tid);
        mm64t(Zs, Ab, Db, Zs, 3.25f, -0.25f, tid);
    }
    for (int e = tid; e < 4096; e += 256) Ab[e] = t3g[(size_t)bh * 4096 + e];
    mm64t(Db, Zs, Ab, nullptr, 0.f, 1.f, tid);
    for (int e = tid; e < 4096; e += 256) t2g[(size_t)bh * 4096 + e] = Db[e];
}

// ---------------- K7: out1 = softmax(mq@k_l^T) @ t2  (MFMA, conv in k_conv) --------
__global__ __launch_bounds__(256) void k_attn1(const float* __restrict__ mq,
    const float* __restrict__ klg, const float* __restrict__ t2g,
    float* __restrict__ opre)
{
    __shared__ __align__(16) _Float16 klh[4096], kll[4096];
    __shared__ __align__(16) _Float16 t2h[4096], t2l[4096];
    __shared__ __align__(16) unsigned int qps[64 * 68];
    const int bh = blockIdx.x;
    const int b = bh >> 3, h = bh & 7;
    const int rgb = blockIdx.y;
    const int tid = threadIdx.x;
    const int wv = tid >> 6, lane = tid & 63;
    const int lg = lane >> 4, ll = lane & 15;

    _Float16* qh_ = (_Float16*)qps;
    _Float16* ql_ = qh_ + 4096;

    #pragma unroll
    for (int it = 0; it < 4; ++it) {
        int e = tid + 256 * it;
        int r = e >> 4, c0 = (e & 15) << 2;
        float4 kx = *(const float4*)(klg + (size_t)bh * 4096 + r * 64 + c0);
        f16x4 hh, lo;
        float vals[4] = {kx.x, kx.y, kx.z, kx.w};
        #pragma unroll
        for (int i = 0; i < 4; ++i) {
            _Float16 hv = (_Float16)vals[i];
            hh[i] = hv; lo[i] = (_Float16)(vals[i] - (float)hv);
        }
        int off = r * 64 + (((c0 >> 3) ^ (r & 7)) << 3) + (c0 & 7);
        *(f16x4*)&klh[off] = hh;
        *(f16x4*)&kll[off] = lo;
    }
    {
        const int r0 = (tid & 31) * 2, cb = (tid >> 5) * 4;
        #pragma unroll
        for (int ci = 0; ci < 2; ++ci) {
            int c0 = cb + 32 * ci;
            float4 v0 = *(const float4*)(t2g + (size_t)bh * 4096 + (size_t)r0 * 64 + c0);
            float4 v1 = *(const float4*)(t2g + (size_t)bh * 4096 + (size_t)(r0 + 1) * 64 + c0);
            float a0[4] = {v0.x, v0.y, v0.z, v0.w};
            float a1[4] = {v1.x, v1.y, v1.z, v1.w};
            #pragma unroll
            for (int i = 0; i < 4; ++i) {
                int c = c0 + i;
                _Float16 h0 = (_Float16)a0[i], h1 = (_Float16)a1[i];
                _Float16 e0 = (_Float16)(a0[i] - (float)h0), e1 = (_Float16)(a1[i] - (float)h1);
                int off = c * 64 + (((r0 >> 3) ^ (c & 7)) << 3) + (r0 & 7);
                *(unsigned int*)&t2h[off] = (unsigned int)hbits(h0) | ((unsigned int)hbits(h1) << 16);
                *(unsigned int*)&t2l[off] = (unsigned int)hbits(e0) | ((unsigned int)hbits(e1) << 16);
            }
        }
    }

    const float* mqb = mq + (size_t)bh * NP * DH;
    f16x8 bkh[2], bkl2[2], bth[2], btl2[2];

    for (int t = 0; t < 8; ++t) {
        const int row0 = (rgb << 9) + (t << 6);
        #pragma unroll
        for (int it = 0; it < 4; ++it) {
            int e = tid + 256 * it;
            int r = e >> 4, c0 = (e & 15) << 2;
            float4 qv = *(const float4*)(mqb + (size_t)(row0 + r) * DH + c0);
            f16x4 hh, lo;
            float vals[4] = {qv.x, qv.y, qv.z, qv.w};
            #pragma unroll
            for (int i = 0; i < 4; ++i) {
                _Float16 hv = (_Float16)vals[i];
                hh[i] = hv; lo[i] = (_Float16)(vals[i] - (float)hv);
            }
            int off = r * 64 + (((c0 >> 3) ^ (r & 7)) << 3) + (c0 & 7);
            *(f16x4*)&qh_[off] = hh;
            *(f16x4*)&ql_[off] = lo;
        }
        __syncthreads();
        if (t == 0) {
            #pragma unroll
            for (int ks = 0; ks < 2; ++ks) {
                int k0 = 32 * ks + (lg << 3);
                int br = 16 * wv + ll;
                int boff = br * 64 + (((k0 >> 3) ^ (br & 7)) << 3);
                bkh[ks]  = *(const f16x8*)&klh[boff];
                bkl2[ks] = *(const f16x8*)&kll[boff];
                bth[ks]  = *(const f16x8*)&t2h[boff];
                btl2[ks] = *(const f16x8*)&t2l[boff];
            }
        }
        f16x8 ah[2][4], al[2][4];
        #pragma unroll
        for (int ks = 0; ks < 2; ++ks) {
            int k0 = 32 * ks + (lg << 3);
            #pragma unroll
            for (int m = 0; m < 4; ++m) {
                int arw = 16 * m + ll;
                int aoff = arw * 64 + (((k0 >> 3) ^ (arw & 7)) << 3);
                ah[ks][m] = *(const f16x8*)&qh_[aoff];
                al[ks][m] = *(const f16x8*)&ql_[aoff];
            }
        }
        __syncthreads();
        f32x4 accs[4] = {};
        #pragma unroll
        for (int ks = 0; ks < 2; ++ks)
            #pragma unroll
            for (int m = 0; m < 4; ++m) {
                accs[m] = __builtin_amdgcn_mfma_f32_16x16x32_f16(ah[ks][m], bkh[ks], accs[m], 0, 0, 0);
                accs[m] = __builtin_amdgcn_mfma_f32_16x16x32_f16(ah[ks][m], bkl2[ks], accs[m], 0, 0, 0);
                accs[m] = __builtin_amdgcn_mfma_f32_16x16x32_f16(al[ks][m], bkh[ks], accs[m], 0, 0, 0);
            }
        #pragma unroll
        for (int m = 0; m < 4; ++m)
            #pragma unroll
            for (int rgi = 0; rgi < 4; ++rgi)
                qps[(16 * m + lg * 4 + rgi) * 68 + 16 * wv + ll] = __float_as_uint(accs[m][rgi]);
        __syncthreads();
        {
            const int r = tid >> 2, q4 = tid & 3;
            float s[16];
            #pragma unroll
            for (int j = 0; j < 16; ++j) s[j] = __uint_as_float(qps[r * 68 + q4 * 16 + j]);
            float rmax = s[0];
            #pragma unroll
            for (int j = 1; j < 16; ++j) rmax = fmaxf(rmax, s[j]);
            rmax = fmaxf(rmax, __shfl_xor(rmax, 1));
            rmax = fmaxf(rmax, __shfl_xor(rmax, 2));
            float p[16], rsum = 0.f;
            #pragma unroll
            for (int j = 0; j < 16; ++j) { p[j] = expf(s[j] - rmax); rsum += p[j]; }
            rsum += __shfl_xor(rsum, 1);
            rsum += __shfl_xor(rsum, 2);
            float rinv = 1.f / rsum;
            #pragma unroll
            for (int j = 0; j < 16; ++j) p[j] *= rinv;
            #pragma unroll
            for (int i2 = 0; i2 < 8; ++i2) {
                float p0 = p[2 * i2], p1 = p[2 * i2 + 1];
                _Float16 h0 = (_Float16)p0, h1 = (_Float16)p1;
                _Float16 e0 = (_Float16)(p0 - (float)h0), e1 = (_Float16)(p1 - (float)h1);
                qps[r * 68 + q4 * 8 + i2]      = (unsigned int)hbits(h0) | ((unsigned int)hbits(h1) << 16);
                qps[r * 68 + 32 + q4 * 8 + i2] = (unsigned int)hbits(e0) | ((unsigned int)hbits(e1) << 16);
            }
        }
        __syncthreads();
        f32x4 acco[4] = {};
        #pragma unroll
        for (int ks = 0; ks < 2; ++ks)
            #pragma unroll
            for (int m = 0; m < 4; ++m) {
                int prow = 16 * m + ll;
                union { uint4 u; f16x8 f; } ph, pe;
                ph.u = *(const uint4*)&qps[prow * 68 + 16 * ks + lg * 4];
                pe.u = *(const uint4*)&qps[prow * 68 + 32 + 16 * ks + lg * 4];
                acco[m] = __builtin_amdgcn_mfma_f32_16x16x32_f16(ph.f, bth[ks], acco[m], 0, 0, 0);
                acco[m] = __builtin_amdgcn_mfma_f32_16x16x32_f16(ph.f, btl2[ks], acco[m], 0, 0, 0);
                acco[m] = __builtin_amdgcn_mfma_f32_16x16x32_f16(pe.f, bth[ks], acco[m], 0, 0, 0);
            }
        {
            int col = 16 * wv + ll;
            #pragma unroll
            for (int m = 0; m < 4; ++m) {
                int rb = row0 + 16 * m + lg * 4;
                #pragma unroll
                for (int rgi = 0; rgi < 4; ++rgi)
                    opre[((size_t)b * NP + rb + rgi) * DIM + h * DH + col] = acco[m][rgi];
            }
        }
        __syncthreads();
    }
}

// ---------------- K7b: opre += depthwise conv(v)  (LDS-staged sliding window) ------------
__global__ __launch_bounds__(256) void k_conv(const float* __restrict__ vb,
    const float* __restrict__ cwg, float* __restrict__ opre)
{
    __shared__ float vs[96][68];
    __shared__ float cw[33];
    const int bh = blockIdx.x;
    const int b = bh >> 3, h = bh & 7;
    const int row0 = blockIdx.y << 6;
    const int tid = threadIdx.x;
    const float* vbase = vb + (size_t)bh * NTOT * DH;
    #pragma unroll
    for (int it = 0; it < 6; ++it) {
        int e = tid + 256 * it;
        int r = e >> 4, c4 = (e & 15) << 2;
        int gr = row0 - 16 + r;
        float4 v = (gr >= 0) ? *(const float4*)(vbase + (size_t)gr * DH + c4)
                             : make_float4(0.f, 0.f, 0.f, 0.f);
        *(float4*)&vs[r][c4] = v;
    }
    if (tid < 33) cw[tid] = cwg[h * 33 + tid];
    __syncthreads();
    const int ty = tid >> 4, c4 = (tid & 15) << 2;
    #pragma unroll
    for (int i = 0; i < 4; ++i) {
        int lr = ty * 4 + i;
        float4 a = make_float4(0.f, 0.f, 0.f, 0.f);
        #pragma unroll 33
        for (int k = 0; k < 33; ++k) {
            float w = cw[k];
            const float* p = &vs[lr + k][c4];
            a.x = fmaf(w, p[0], a.x); a.y = fmaf(w, p[1], a.y);
            a.z = fmaf(w, p[2], a.z); a.w = fmaf(w, p[3], a.w);
        }
        float* op = opre + ((size_t)b * NP + row0 + lr) * DIM + h * DH + c4;
        float4 o = *(const float4*)op;
        o.x += a.x; o.y += a.y; o.z += a.z; o.w += a.w;
        *(float4*)op = o;
    }
}

extern "C" void kernel_launch(void* const* d_in, const int* in_sizes, int n_in,
                              void* d_out, int out_size, void* d_ws, size_t ws_size,
                              hipStream_t stream)
{
    const float* x   = (const float*)d_in[0];
    const float* ps  = (const float*)d_in[1];
    const float* wq  = (const float*)d_in[2];
    const float* wo  = (const float*)d_in[3];
    const float* cwg = (const float*)d_in[4];
    float* out = (float*)d_out;
    float* ws  = (float*)d_ws;

    float* mq   = out;               // d_out doubles as mq scratch; k_gemm<1> overwrites last
    float* kb   = ws + OFF_K;
    float* vb   = ws + OFF_V;
    float* kl   = ws + OFF_KL;       // written by k_landc (after BTq dead)
    float* a2   = ws + OFF_A2;
    float* t3   = ws + OFF_T3;
    float* t2   = ws + OFF_T2;
    float* mx   = ws + OFF_MAX;
    float* opre = ws + OFF_OPRE;
    float* qla  = ws + OFF_QLA;      // q landmarks, written directly by gemm<0> epilogue
    float* klp  = ws + OFF_KLP;      // k landmark 64-row partials
    float* pacc = opre;
    float* pm   = opre + 3145728ull;
    float* pl   = pm + 49152ull;
    _Float16* BTqh = (_Float16*)(ws + OFF_QL);
    _Float16* BTql = BTqh + 1536 * 512;
    _Float16* BToh = (_Float16*)(ws + OFF_K);
    _Float16* BTol = BToh + 512 * 512;

    k_cvtw        <<<dim3(24, 8), 256, 0, stream>>>(wq, BTqh, BTql, 512, 1536);
    k_gemm_split<0><<<4608, 256, 0, stream>>>(x, ps, BTqh, BTql, mq, kb, vb, qla, klp);
    k_landc       <<<32, 256, 0, stream>>>(klp, kl);
    k_sim2        <<<32, 256, 0, stream>>>(qla, kl, a2, mx);
    k_maxes       <<<32, 64, 0, stream>>>(a2, mx);
    k_sim3part    <<<dim3(32, NCH), 256, 0, stream>>>(qla, kb, vb, pacc, pm, pl);
    k_sim3comb    <<<32, 256, 0, stream>>>(pacc, pm, pl, t3);
    k_cvtw        <<<dim3(8, 8), 256, 0, stream>>>(wo, BToh, BTol, 512, 512);
    k_pinv        <<<32, 256, 0, stream>>>(a2, mx, t3, t2);
    k_attn1       <<<dim3(32, 8), 256, 0, stream>>>(mq, kl, t2, opre);
    k_conv        <<<dim3(32, 64), 256, 0, stream>>>(vb, cwg, opre);
    k_gemm_split<1><<<512, 256, 0, stream>>>(opre, nullptr, BToh, BTol, out, nullptr, nullptr, nullptr, nullptr);
}